// Round 1
// baseline (950.739 us; speedup 1.0000x reference)
//
#include <hip/hip_runtime.h>

#define CH 128

// ---------------------------------------------------------------------------
// Detect whether edge_index is int64 or int32 on device.
// For int64 data with non-negative values < 2^31, every odd int32 word
// (the high half) is zero. For genuine int32 random indices in [0, 100000),
// the odds of words 1,3,5,7 all being zero are ~1e-20.
// ---------------------------------------------------------------------------
__global__ void detect_i64(const int* __restrict__ ei, int* __restrict__ flag) {
    if (threadIdx.x == 0 && blockIdx.x == 0) {
        int hi_zero = (ei[1] == 0) && (ei[3] == 0) && (ei[5] == 0) && (ei[7] == 0);
        int lo_any  = (ei[0] | ei[2] | ei[4] | ei[6]) != 0;
        *flag = (hi_zero && lo_any) ? 1 : 0;
    }
}

// ---------------------------------------------------------------------------
// Edge-parallel scatter: agg[dst] += x[src]; cnt[dst] += 1.
// One 64-lane wave per edge, 2 channels per lane (coalesced 256B row halves).
// ---------------------------------------------------------------------------
__global__ __launch_bounds__(256) void scatter_kernel(
    const float* __restrict__ x,
    const void* __restrict__ edges,
    float* __restrict__ agg,
    float* __restrict__ cnt,
    const int* __restrict__ flag,
    int n_edges)
{
    int e = blockIdx.x * 4 + (threadIdx.x >> 6);
    if (e >= n_edges) return;
    int lane = threadIdx.x & 63;

    long long s, d;
    if (*flag) {
        const long long* ei = (const long long*)edges;
        s = ei[e];
        d = ei[e + n_edges];
    } else {
        const int* ei = (const int*)edges;
        s = ei[e];
        d = ei[e + n_edges];
    }

    const float* xs = x + s * (long long)CH;
    float*       ad = agg + d * (long long)CH;

    float v0 = xs[lane];
    float v1 = xs[lane + 64];
    unsafeAtomicAdd(ad + lane,      v0);
    unsafeAtomicAdd(ad + lane + 64, v1);
    if (lane == 0) unsafeAtomicAdd(cnt + d, 1.0f);
}

// ---------------------------------------------------------------------------
// Fused epilogue: out = relu((agg/max(cnt,1)) @ W_l + x @ W_r + b)
// 16 nodes per 256-thread block. x/mean rows staged in LDS (16 KB).
// Each thread computes 2 nodes x 4 channels; W read as float4 (L2-resident).
// NOTE: agg/out may alias (fallback path) -> no __restrict__ on them; all
// reads of agg happen before __syncthreads(), all writes to out after.
// ---------------------------------------------------------------------------
#define NB 16

__global__ __launch_bounds__(256) void sage_out_kernel(
    const float* __restrict__ x,
    const float* agg,
    const float* __restrict__ cnt,
    const float* __restrict__ Wl,
    const float* __restrict__ Wr,
    const float* __restrict__ b,
    float* out,
    int n_nodes)
{
    __shared__ float s_mean[NB][CH];
    __shared__ float s_x[NB][CH];

    const int node0 = blockIdx.x * NB;
    const int tid   = threadIdx.x;

    // Cooperative load of NB rows of agg (scaled to mean) and x.
    for (int i = tid; i < NB * CH; i += 256) {
        int n = i >> 7;
        int c = i & (CH - 1);
        int node = node0 + n;
        float a = 0.0f, xv = 0.0f, inv = 1.0f;
        if (node < n_nodes) {
            float cn = cnt[node];
            inv = 1.0f / fmaxf(cn, 1.0f);
            a  = agg[(long long)node * CH + c];
            xv = x[(long long)node * CH + c];
        }
        s_mean[n][c] = a * inv;
        s_x[n][c]    = xv;
    }
    __syncthreads();

    const int cg    = (tid & 31) * 4;   // channel group: 0..124
    const int nbase = (tid >> 5) * 2;   // node pair: 0,2,..,14

    float acc0[4] = {0.f, 0.f, 0.f, 0.f};
    float acc1[4] = {0.f, 0.f, 0.f, 0.f};

#pragma unroll 8
    for (int k = 0; k < CH; ++k) {
        float4 wl = *(const float4*)(Wl + k * CH + cg);
        float4 wr = *(const float4*)(Wr + k * CH + cg);
        float m0 = s_mean[nbase][k];
        float m1 = s_mean[nbase + 1][k];
        float x0 = s_x[nbase][k];
        float x1 = s_x[nbase + 1][k];
        acc0[0] += m0 * wl.x + x0 * wr.x;
        acc0[1] += m0 * wl.y + x0 * wr.y;
        acc0[2] += m0 * wl.z + x0 * wr.z;
        acc0[3] += m0 * wl.w + x0 * wr.w;
        acc1[0] += m1 * wl.x + x1 * wr.x;
        acc1[1] += m1 * wl.y + x1 * wr.y;
        acc1[2] += m1 * wl.z + x1 * wr.z;
        acc1[3] += m1 * wl.w + x1 * wr.w;
    }

    float4 bb = *(const float4*)(b + cg);
    int n0 = node0 + nbase;
    int n1 = n0 + 1;
    if (n0 < n_nodes) {
        float4 o;
        o.x = fmaxf(acc0[0] + bb.x, 0.0f);
        o.y = fmaxf(acc0[1] + bb.y, 0.0f);
        o.z = fmaxf(acc0[2] + bb.z, 0.0f);
        o.w = fmaxf(acc0[3] + bb.w, 0.0f);
        *(float4*)(out + (long long)n0 * CH + cg) = o;
    }
    if (n1 < n_nodes) {
        float4 o;
        o.x = fmaxf(acc1[0] + bb.x, 0.0f);
        o.y = fmaxf(acc1[1] + bb.y, 0.0f);
        o.z = fmaxf(acc1[2] + bb.z, 0.0f);
        o.w = fmaxf(acc1[3] + bb.w, 0.0f);
        *(float4*)(out + (long long)n1 * CH + cg) = o;
    }
}

extern "C" void kernel_launch(void* const* d_in, const int* in_sizes, int n_in,
                              void* d_out, int out_size, void* d_ws, size_t ws_size,
                              hipStream_t stream)
{
    const float* x     = (const float*)d_in[0];
    const void*  edges = d_in[1];
    const float* Wl    = (const float*)d_in[2];
    const float* Wr    = (const float*)d_in[3];
    const float* b     = (const float*)d_in[4];
    float*       out   = (float*)d_out;

    const int n_nodes = in_sizes[0] / CH;
    const int n_edges = in_sizes[1] / 2;

    const size_t agg_bytes = (size_t)n_nodes * CH * sizeof(float);
    const size_t cnt_bytes = (size_t)n_nodes * sizeof(float);

    float* agg;
    float* cnt;
    int*   flag;
    char*  ws = (char*)d_ws;

    if (ws_size >= agg_bytes + cnt_bytes + 256) {
        agg  = (float*)ws;
        cnt  = (float*)(ws + agg_bytes);
        flag = (int*)(ws + agg_bytes + cnt_bytes);
    } else {
        // Fallback: accumulate directly in d_out (row-wise in-place is safe).
        agg  = out;
        cnt  = (float*)ws;
        flag = (int*)(ws + cnt_bytes);
    }

    hipMemsetAsync(agg, 0, agg_bytes, stream);
    hipMemsetAsync(cnt, 0, cnt_bytes, stream);

    detect_i64<<<1, 1, 0, stream>>>((const int*)edges, flag);

    const int eblocks = (n_edges + 3) / 4;
    scatter_kernel<<<eblocks, 256, 0, stream>>>(x, edges, agg, cnt, flag, n_edges);

    const int oblocks = (n_nodes + NB - 1) / NB;
    sage_out_kernel<<<oblocks, 256, 0, stream>>>(x, agg, cnt, Wl, Wr, b, out, n_nodes);
}

// Round 2
// 602.527 us; speedup vs baseline: 1.5779x; 1.5779x over previous
//
#include <hip/hip_runtime.h>

#define CH 128
#define NB 16
#define SC_T 256
#define SC_I 8            // 2048 deg entries scanned per block

// ---------------------------------------------------------------------------
// Detect whether edge_index is int64 or int32 on device (odd words all zero
// => int64 with values < 2^31).
// ---------------------------------------------------------------------------
__global__ void detect_i64(const int* __restrict__ ei, int* __restrict__ flag) {
    if (threadIdx.x == 0 && blockIdx.x == 0) {
        int hi_zero = (ei[1] == 0) && (ei[3] == 0) && (ei[5] == 0) && (ei[7] == 0);
        int lo_any  = (ei[0] | ei[2] | ei[4] | ei[6]) != 0;
        *flag = (hi_zero && lo_any) ? 1 : 0;
    }
}

__device__ __forceinline__ int load_dst(const void* edges, int e, int n_edges, int f) {
    const int* p = (const int*)edges;
    return f ? p[2 * (e + n_edges)] : p[e + n_edges];
}
__device__ __forceinline__ int load_src(const void* edges, int e, int f) {
    const int* p = (const int*)edges;
    return f ? p[2 * e] : p[e];
}

// ---------------------------------------------------------------------------
// 1) degree histogram
// ---------------------------------------------------------------------------
__global__ __launch_bounds__(256) void hist_kernel(
    const void* __restrict__ edges, const int* __restrict__ flag,
    int* __restrict__ deg, int n_edges)
{
    int e = blockIdx.x * 256 + threadIdx.x;
    if (e >= n_edges) return;
    atomicAdd(&deg[load_dst(edges, e, n_edges, *flag)], 1);
}

// ---------------------------------------------------------------------------
// 2) exclusive scan of deg -> offs (3 kernels)
// ---------------------------------------------------------------------------
__global__ __launch_bounds__(SC_T) void scan_blocks(
    const int* __restrict__ deg, int* __restrict__ offs,
    int* __restrict__ bsums, int n)
{
    __shared__ int s_sum[SC_T];
    const int t = threadIdx.x;
    const int base = blockIdx.x * SC_T * SC_I + t * SC_I;
    int v[SC_I];
    int tsum = 0;
#pragma unroll
    for (int i = 0; i < SC_I; ++i) {
        int idx = base + i;
        v[i] = (idx < n) ? deg[idx] : 0;
        tsum += v[i];
    }
    s_sum[t] = tsum;
    __syncthreads();
    for (int off = 1; off < SC_T; off <<= 1) {
        int val = (t >= off) ? s_sum[t - off] : 0;
        __syncthreads();
        s_sum[t] += val;
        __syncthreads();
    }
    int run = s_sum[t] - tsum;   // exclusive prefix of this thread's segment
#pragma unroll
    for (int i = 0; i < SC_I; ++i) {
        int idx = base + i;
        if (idx < n) offs[idx] = run;
        run += v[i];
    }
    if (t == SC_T - 1) bsums[blockIdx.x] = s_sum[t];
}

__global__ __launch_bounds__(SC_T) void scan_totals(int* __restrict__ bsums, int nb)
{
    __shared__ int s[SC_T];
    const int t = threadIdx.x;
    int orig = (t < nb) ? bsums[t] : 0;
    s[t] = orig;
    __syncthreads();
    for (int off = 1; off < SC_T; off <<= 1) {
        int val = (t >= off) ? s[t - off] : 0;
        __syncthreads();
        s[t] += val;
        __syncthreads();
    }
    if (t < nb) bsums[t] = s[t] - orig;   // exclusive
}

__global__ __launch_bounds__(256) void fixup_kernel(
    int* __restrict__ offs, const int* __restrict__ bsums,
    int* __restrict__ cursor, int n)
{
    int i = blockIdx.x * 256 + threadIdx.x;
    if (i >= n) return;
    int o = offs[i] + bsums[i / (SC_T * SC_I)];
    offs[i] = o;
    cursor[i] = o;
}

// ---------------------------------------------------------------------------
// 3) scatter src ids into dst-sorted order
// ---------------------------------------------------------------------------
__global__ __launch_bounds__(256) void sort_kernel(
    const void* __restrict__ edges, const int* __restrict__ flag,
    int* __restrict__ cursor, int* __restrict__ sorted, int n_edges)
{
    int e = blockIdx.x * 256 + threadIdx.x;
    if (e >= n_edges) return;
    int f = *flag;
    int d = load_dst(edges, e, n_edges, f);
    int s = load_src(edges, e, f);
    int pos = atomicAdd(&cursor[d], 1);
    sorted[pos] = s;
}

// ---------------------------------------------------------------------------
// 4) fused gather-mean + GEMM epilogue:
//    out = relu(mean @ W_l + x @ W_r + b)
//    16 nodes/block; wave w gathers nodes 4w..4w+3 via sorted neighbor lists.
// ---------------------------------------------------------------------------
__global__ __launch_bounds__(256) void fused_kernel(
    const float* __restrict__ x,
    const int* __restrict__ sorted,
    const int* __restrict__ deg,
    const int* __restrict__ offs,
    const float* __restrict__ Wl,
    const float* __restrict__ Wr,
    const float* __restrict__ b,
    float* __restrict__ out,
    int n_nodes)
{
    __shared__ float s_mean[NB][CH];
    __shared__ float s_x[NB][CH];

    const int node0 = blockIdx.x * NB;
    const int tid   = threadIdx.x;
    const int wave  = tid >> 6;
    const int lane  = tid & 63;

    // x rows, coalesced
    for (int i = tid; i < NB * CH; i += 256) {
        int n = i >> 7, c = i & (CH - 1);
        int node = node0 + n;
        s_x[n][c] = (node < n_nodes) ? x[(long long)node * CH + c] : 0.0f;
    }

    // gather-mean: 4 nodes per wave
    for (int nn = 0; nn < 4; ++nn) {
        int n = wave * 4 + nn;
        int node = node0 + n;
        float a0 = 0.0f, a1 = 0.0f;
        if (node < n_nodes) {
            int base = offs[node];
            int dg   = deg[node];
            for (int j0 = 0; j0 < dg; j0 += 64) {
                int m  = min(64, dg - j0);
                int sv = (j0 + lane < dg) ? sorted[base + j0 + lane] : 0;
#pragma unroll 4
                for (int j = 0; j < m; ++j) {
                    int s = __shfl(sv, j);
                    const float* xs = x + (long long)s * CH;
                    a0 += xs[lane];
                    a1 += xs[lane + 64];
                }
            }
            float inv = 1.0f / fmaxf((float)dg, 1.0f);
            a0 *= inv; a1 *= inv;
        }
        s_mean[n][lane]      = a0;
        s_mean[n][lane + 64] = a1;
    }
    __syncthreads();

    const int cg    = (tid & 31) * 4;
    const int nbase = (tid >> 5) * 2;

    float acc0[4] = {0.f, 0.f, 0.f, 0.f};
    float acc1[4] = {0.f, 0.f, 0.f, 0.f};

#pragma unroll 8
    for (int k = 0; k < CH; ++k) {
        float4 wl = *(const float4*)(Wl + k * CH + cg);
        float4 wr = *(const float4*)(Wr + k * CH + cg);
        float m0 = s_mean[nbase][k];
        float m1 = s_mean[nbase + 1][k];
        float x0 = s_x[nbase][k];
        float x1 = s_x[nbase + 1][k];
        acc0[0] += m0 * wl.x + x0 * wr.x;
        acc0[1] += m0 * wl.y + x0 * wr.y;
        acc0[2] += m0 * wl.z + x0 * wr.z;
        acc0[3] += m0 * wl.w + x0 * wr.w;
        acc1[0] += m1 * wl.x + x1 * wr.x;
        acc1[1] += m1 * wl.y + x1 * wr.y;
        acc1[2] += m1 * wl.z + x1 * wr.z;
        acc1[3] += m1 * wl.w + x1 * wr.w;
    }

    float4 bb = *(const float4*)(b + cg);
    int n0 = node0 + nbase, n1 = n0 + 1;
    if (n0 < n_nodes) {
        float4 o;
        o.x = fmaxf(acc0[0] + bb.x, 0.0f);
        o.y = fmaxf(acc0[1] + bb.y, 0.0f);
        o.z = fmaxf(acc0[2] + bb.z, 0.0f);
        o.w = fmaxf(acc0[3] + bb.w, 0.0f);
        *(float4*)(out + (long long)n0 * CH + cg) = o;
    }
    if (n1 < n_nodes) {
        float4 o;
        o.x = fmaxf(acc1[0] + bb.x, 0.0f);
        o.y = fmaxf(acc1[1] + bb.y, 0.0f);
        o.z = fmaxf(acc1[2] + bb.z, 0.0f);
        o.w = fmaxf(acc1[3] + bb.w, 0.0f);
        *(float4*)(out + (long long)n1 * CH + cg) = o;
    }
}

// ---------------------------------------------------------------------------
// Fallback path (tiny workspace): atomic scatter into out + separate epilogue.
// ---------------------------------------------------------------------------
__global__ __launch_bounds__(256) void scatter_kernel(
    const float* __restrict__ x, const void* __restrict__ edges,
    float* __restrict__ agg, float* __restrict__ cnt,
    const int* __restrict__ flag, int n_edges)
{
    int e = blockIdx.x * 4 + (threadIdx.x >> 6);
    if (e >= n_edges) return;
    int lane = threadIdx.x & 63;
    int f = *flag;
    long long s = load_src(edges, e, f);
    long long d = load_dst(edges, e, n_edges, f);
    const float* xs = x + s * (long long)CH;
    float*       ad = agg + d * (long long)CH;
    unsafeAtomicAdd(ad + lane,      xs[lane]);
    unsafeAtomicAdd(ad + lane + 64, xs[lane + 64]);
    if (lane == 0) unsafeAtomicAdd(cnt + d, 1.0f);
}

__global__ __launch_bounds__(256) void sage_out_kernel(
    const float* __restrict__ x, const float* agg, const float* __restrict__ cnt,
    const float* __restrict__ Wl, const float* __restrict__ Wr,
    const float* __restrict__ b, float* out, int n_nodes)
{
    __shared__ float s_mean[NB][CH];
    __shared__ float s_x[NB][CH];
    const int node0 = blockIdx.x * NB;
    const int tid   = threadIdx.x;
    for (int i = tid; i < NB * CH; i += 256) {
        int n = i >> 7, c = i & (CH - 1);
        int node = node0 + n;
        float a = 0.0f, xv = 0.0f, inv = 1.0f;
        if (node < n_nodes) {
            inv = 1.0f / fmaxf(cnt[node], 1.0f);
            a  = agg[(long long)node * CH + c];
            xv = x[(long long)node * CH + c];
        }
        s_mean[n][c] = a * inv;
        s_x[n][c]    = xv;
    }
    __syncthreads();
    const int cg = (tid & 31) * 4, nbase = (tid >> 5) * 2;
    float acc0[4] = {0,0,0,0}, acc1[4] = {0,0,0,0};
#pragma unroll 8
    for (int k = 0; k < CH; ++k) {
        float4 wl = *(const float4*)(Wl + k * CH + cg);
        float4 wr = *(const float4*)(Wr + k * CH + cg);
        float m0 = s_mean[nbase][k],   m1 = s_mean[nbase + 1][k];
        float x0 = s_x[nbase][k],      x1 = s_x[nbase + 1][k];
        acc0[0] += m0*wl.x + x0*wr.x;  acc0[1] += m0*wl.y + x0*wr.y;
        acc0[2] += m0*wl.z + x0*wr.z;  acc0[3] += m0*wl.w + x0*wr.w;
        acc1[0] += m1*wl.x + x1*wr.x;  acc1[1] += m1*wl.y + x1*wr.y;
        acc1[2] += m1*wl.z + x1*wr.z;  acc1[3] += m1*wl.w + x1*wr.w;
    }
    float4 bb = *(const float4*)(b + cg);
    int n0 = node0 + nbase, n1 = n0 + 1;
    if (n0 < n_nodes) {
        float4 o = { fmaxf(acc0[0]+bb.x,0.f), fmaxf(acc0[1]+bb.y,0.f),
                     fmaxf(acc0[2]+bb.z,0.f), fmaxf(acc0[3]+bb.w,0.f) };
        *(float4*)(out + (long long)n0 * CH + cg) = o;
    }
    if (n1 < n_nodes) {
        float4 o = { fmaxf(acc1[0]+bb.x,0.f), fmaxf(acc1[1]+bb.y,0.f),
                     fmaxf(acc1[2]+bb.z,0.f), fmaxf(acc1[3]+bb.w,0.f) };
        *(float4*)(out + (long long)n1 * CH + cg) = o;
    }
}

extern "C" void kernel_launch(void* const* d_in, const int* in_sizes, int n_in,
                              void* d_out, int out_size, void* d_ws, size_t ws_size,
                              hipStream_t stream)
{
    const float* x     = (const float*)d_in[0];
    const void*  edges = d_in[1];
    const float* Wl    = (const float*)d_in[2];
    const float* Wr    = (const float*)d_in[3];
    const float* b     = (const float*)d_in[4];
    float*       out   = (float*)d_out;

    const int n_nodes = in_sizes[0] / CH;
    const int n_edges = in_sizes[1] / 2;

    char* ws = (char*)d_ws;
    const size_t ints_n   = (size_t)n_nodes * sizeof(int);
    const int    nscan    = (n_nodes + SC_T * SC_I - 1) / (SC_T * SC_I);
    const size_t need     = 3 * ints_n                       // deg, offs, cursor
                          + 1024 * sizeof(int)               // bsums (padded)
                          + 64                               // flag
                          + (size_t)n_edges * sizeof(int);   // sorted

    if (ws_size >= need && nscan <= SC_T) {
        int* deg    = (int*)ws;
        int* offs   = (int*)(ws + ints_n);
        int* cursor = (int*)(ws + 2 * ints_n);
        int* bsums  = (int*)(ws + 3 * ints_n);
        int* flag   = (int*)(ws + 3 * ints_n + 1024 * sizeof(int));
        int* sorted = (int*)(ws + 3 * ints_n + 1024 * sizeof(int) + 64);

        hipMemsetAsync(deg, 0, ints_n, stream);
        detect_i64<<<1, 1, 0, stream>>>((const int*)edges, flag);

        const int eb = (n_edges + 255) / 256;
        hist_kernel<<<eb, 256, 0, stream>>>(edges, flag, deg, n_edges);
        scan_blocks<<<nscan, SC_T, 0, stream>>>(deg, offs, bsums, n_nodes);
        scan_totals<<<1, SC_T, 0, stream>>>(bsums, nscan);
        fixup_kernel<<<(n_nodes + 255) / 256, 256, 0, stream>>>(offs, bsums, cursor, n_nodes);
        sort_kernel<<<eb, 256, 0, stream>>>(edges, flag, cursor, sorted, n_edges);

        const int ob = (n_nodes + NB - 1) / NB;
        fused_kernel<<<ob, 256, 0, stream>>>(x, sorted, deg, offs, Wl, Wr, b, out, n_nodes);
    } else {
        // Fallback: atomic scatter into d_out, epilogue reads it back.
        float* agg = out;
        float* cnt = (float*)ws;
        int*   flag = (int*)(ws + ints_n);
        hipMemsetAsync(agg, 0, (size_t)n_nodes * CH * sizeof(float), stream);
        hipMemsetAsync(cnt, 0, ints_n, stream);
        detect_i64<<<1, 1, 0, stream>>>((const int*)edges, flag);
        scatter_kernel<<<(n_edges + 3) / 4, 256, 0, stream>>>(x, edges, agg, cnt, flag, n_edges);
        sage_out_kernel<<<(n_nodes + NB - 1) / NB, 256, 0, stream>>>(x, agg, cnt, Wl, Wr, b, out, n_nodes);
    }
}

// Round 3
// 494.634 us; speedup vs baseline: 1.9221x; 1.2181x over previous
//
#include <hip/hip_runtime.h>

#define CH 128
#define NB 64
#define LPAD 4
#define LSTR (NB + LPAD)      // 68 floats: 16B-aligned rows, broadcast-friendly
#define FB_NB 16
#define SC_T 256
#define SC_I 8                // 2048 deg entries scanned per block

// ---------------------------------------------------------------------------
// Detect whether edge_index is int64 or int32 on device (odd words all zero
// => int64 with values < 2^31).
// ---------------------------------------------------------------------------
__global__ void detect_i64(const int* __restrict__ ei, int* __restrict__ flag) {
    if (threadIdx.x == 0 && blockIdx.x == 0) {
        int hi_zero = (ei[1] == 0) && (ei[3] == 0) && (ei[5] == 0) && (ei[7] == 0);
        int lo_any  = (ei[0] | ei[2] | ei[4] | ei[6]) != 0;
        *flag = (hi_zero && lo_any) ? 1 : 0;
    }
}

__device__ __forceinline__ int load_dst(const void* edges, int e, int n_edges, int f) {
    const int* p = (const int*)edges;
    return f ? p[2 * (e + n_edges)] : p[e + n_edges];
}
__device__ __forceinline__ int load_src(const void* edges, int e, int f) {
    const int* p = (const int*)edges;
    return f ? p[2 * e] : p[e];
}

// ---------------------------------------------------------------------------
// 1) degree histogram
// ---------------------------------------------------------------------------
__global__ __launch_bounds__(256) void hist_kernel(
    const void* __restrict__ edges, const int* __restrict__ flag,
    int* __restrict__ deg, int n_edges)
{
    int e = blockIdx.x * 256 + threadIdx.x;
    if (e >= n_edges) return;
    atomicAdd(&deg[load_dst(edges, e, n_edges, *flag)], 1);
}

// ---------------------------------------------------------------------------
// 2) exclusive scan of deg -> offs (3 kernels)
// ---------------------------------------------------------------------------
__global__ __launch_bounds__(SC_T) void scan_blocks(
    const int* __restrict__ deg, int* __restrict__ offs,
    int* __restrict__ bsums, int n)
{
    __shared__ int s_sum[SC_T];
    const int t = threadIdx.x;
    const int base = blockIdx.x * SC_T * SC_I + t * SC_I;
    int v[SC_I];
    int tsum = 0;
#pragma unroll
    for (int i = 0; i < SC_I; ++i) {
        int idx = base + i;
        v[i] = (idx < n) ? deg[idx] : 0;
        tsum += v[i];
    }
    s_sum[t] = tsum;
    __syncthreads();
    for (int off = 1; off < SC_T; off <<= 1) {
        int val = (t >= off) ? s_sum[t - off] : 0;
        __syncthreads();
        s_sum[t] += val;
        __syncthreads();
    }
    int run = s_sum[t] - tsum;
#pragma unroll
    for (int i = 0; i < SC_I; ++i) {
        int idx = base + i;
        if (idx < n) offs[idx] = run;
        run += v[i];
    }
    if (t == SC_T - 1) bsums[blockIdx.x] = s_sum[t];
}

__global__ __launch_bounds__(SC_T) void scan_totals(int* __restrict__ bsums, int nb)
{
    __shared__ int s[SC_T];
    const int t = threadIdx.x;
    int orig = (t < nb) ? bsums[t] : 0;
    s[t] = orig;
    __syncthreads();
    for (int off = 1; off < SC_T; off <<= 1) {
        int val = (t >= off) ? s[t - off] : 0;
        __syncthreads();
        s[t] += val;
        __syncthreads();
    }
    if (t < nb) bsums[t] = s[t] - orig;
}

__global__ __launch_bounds__(256) void fixup_kernel(
    int* __restrict__ offs, const int* __restrict__ bsums,
    int* __restrict__ cursor, int n)
{
    int i = blockIdx.x * 256 + threadIdx.x;
    if (i >= n) return;
    int o = offs[i] + bsums[i / (SC_T * SC_I)];
    offs[i] = o;
    cursor[i] = o;
}

// ---------------------------------------------------------------------------
// 3) scatter src ids into dst-sorted order
// ---------------------------------------------------------------------------
__global__ __launch_bounds__(256) void sort_kernel(
    const void* __restrict__ edges, const int* __restrict__ flag,
    int* __restrict__ cursor, int* __restrict__ sorted, int n_edges)
{
    int e = blockIdx.x * 256 + threadIdx.x;
    if (e >= n_edges) return;
    int f = *flag;
    int d = load_dst(edges, e, n_edges, f);
    int s = load_src(edges, e, f);
    int pos = atomicAdd(&cursor[d], 1);
    sorted[pos] = s;
}

// ---------------------------------------------------------------------------
// 4) fused gather-mean + GEMM epilogue, 64 nodes/block.
//    Transposed LDS staging s[CH][LSTR]; thread computes 8 nodes x 4 ch.
// ---------------------------------------------------------------------------
__global__ __launch_bounds__(256) void fused_kernel(
    const float* __restrict__ x,
    const int* __restrict__ sorted,
    const int* __restrict__ deg,
    const int* __restrict__ offs,
    const float* __restrict__ Wl,
    const float* __restrict__ Wr,
    const float* __restrict__ b,
    float* __restrict__ out,
    int n_nodes)
{
    __shared__ float s_m[CH][LSTR];   // mean, transposed [k][node]
    __shared__ float s_v[CH][LSTR];   // x,    transposed [k][node]

    const int node0 = blockIdx.x * NB;
    const int tid   = threadIdx.x;
    const int wave  = tid >> 6;
    const int lane  = tid & 63;

    // ---- gather-mean + x staging: wave handles 16 consecutive nodes ----
    for (int nn = 0; nn < 16; ++nn) {
        int n    = wave * 16 + nn;
        int node = node0 + n;
        float a0 = 0.f, a1 = 0.f, x0 = 0.f, x1 = 0.f;
        if (node < n_nodes) {
            const float* xr = x + (long long)node * CH;
            x0 = xr[lane];
            x1 = xr[lane + 64];
            int base = offs[node];
            int dg   = deg[node];
            for (int j0 = 0; j0 < dg; j0 += 64) {
                int m  = min(64, dg - j0);
                int sv = (j0 + lane < dg) ? sorted[base + j0 + lane] : 0;
                int jj = 0;
                // 8-edge prefetch: 16 independent loads in flight
                for (; jj + 8 <= m; jj += 8) {
                    float v0[8], v1[8];
#pragma unroll
                    for (int u = 0; u < 8; ++u) {
                        int s = __shfl(sv, jj + u);
                        const float* p = x + (long long)s * CH;
                        v0[u] = p[lane];
                        v1[u] = p[lane + 64];
                    }
#pragma unroll
                    for (int u = 0; u < 8; ++u) { a0 += v0[u]; a1 += v1[u]; }
                }
                for (; jj < m; ++jj) {
                    int s = __shfl(sv, jj);
                    const float* p = x + (long long)s * CH;
                    a0 += p[lane];
                    a1 += p[lane + 64];
                }
            }
            float inv = 1.0f / fmaxf((float)dg, 1.0f);
            a0 *= inv; a1 *= inv;
        }
        s_m[lane][n]      = a0;
        s_m[lane + 64][n] = a1;
        s_v[lane][n]      = x0;
        s_v[lane + 64][n] = x1;
    }
    __syncthreads();

    // ---- GEMM: out = relu(mean @ Wl + x @ Wr + b) ----
    const int cg = (tid & 31) * 4;      // 4 output channels
    const int ng = (tid >> 5) * 8;      // 8 nodes

    float acc[8][4];
#pragma unroll
    for (int u = 0; u < 8; ++u)
#pragma unroll
        for (int j = 0; j < 4; ++j) acc[u][j] = 0.f;

#pragma unroll 4
    for (int k = 0; k < CH; ++k) {
        const float* mr = &s_m[k][ng];
        const float* vr = &s_v[k][ng];
        float4 wl = *(const float4*)(Wl + k * CH + cg);
        float4 wr = *(const float4*)(Wr + k * CH + cg);
#pragma unroll
        for (int u = 0; u < 8; ++u) {
            float m  = mr[u];
            float xv = vr[u];
            acc[u][0] += m * wl.x + xv * wr.x;
            acc[u][1] += m * wl.y + xv * wr.y;
            acc[u][2] += m * wl.z + xv * wr.z;
            acc[u][3] += m * wl.w + xv * wr.w;
        }
    }

    float4 bb = *(const float4*)(b + cg);
#pragma unroll
    for (int u = 0; u < 8; ++u) {
        int node = node0 + ng + u;
        if (node < n_nodes) {
            float4 o;
            o.x = fmaxf(acc[u][0] + bb.x, 0.0f);
            o.y = fmaxf(acc[u][1] + bb.y, 0.0f);
            o.z = fmaxf(acc[u][2] + bb.z, 0.0f);
            o.w = fmaxf(acc[u][3] + bb.w, 0.0f);
            *(float4*)(out + (long long)node * CH + cg) = o;
        }
    }
}

// ---------------------------------------------------------------------------
// Fallback path (tiny workspace): atomic scatter into out + separate epilogue.
// ---------------------------------------------------------------------------
__global__ __launch_bounds__(256) void scatter_kernel(
    const float* __restrict__ x, const void* __restrict__ edges,
    float* __restrict__ agg, float* __restrict__ cnt,
    const int* __restrict__ flag, int n_edges)
{
    int e = blockIdx.x * 4 + (threadIdx.x >> 6);
    if (e >= n_edges) return;
    int lane = threadIdx.x & 63;
    int f = *flag;
    long long s = load_src(edges, e, f);
    long long d = load_dst(edges, e, n_edges, f);
    const float* xs = x + s * (long long)CH;
    float*       ad = agg + d * (long long)CH;
    unsafeAtomicAdd(ad + lane,      xs[lane]);
    unsafeAtomicAdd(ad + lane + 64, xs[lane + 64]);
    if (lane == 0) unsafeAtomicAdd(cnt + d, 1.0f);
}

__global__ __launch_bounds__(256) void sage_out_kernel(
    const float* __restrict__ x, const float* agg, const float* __restrict__ cnt,
    const float* __restrict__ Wl, const float* __restrict__ Wr,
    const float* __restrict__ b, float* out, int n_nodes)
{
    __shared__ float s_mean[FB_NB][CH];
    __shared__ float s_x[FB_NB][CH];
    const int node0 = blockIdx.x * FB_NB;
    const int tid   = threadIdx.x;
    for (int i = tid; i < FB_NB * CH; i += 256) {
        int n = i >> 7, c = i & (CH - 1);
        int node = node0 + n;
        float a = 0.0f, xv = 0.0f, inv = 1.0f;
        if (node < n_nodes) {
            inv = 1.0f / fmaxf(cnt[node], 1.0f);
            a  = agg[(long long)node * CH + c];
            xv = x[(long long)node * CH + c];
        }
        s_mean[n][c] = a * inv;
        s_x[n][c]    = xv;
    }
    __syncthreads();
    const int cg = (tid & 31) * 4, nbase = (tid >> 5) * 2;
    float acc0[4] = {0,0,0,0}, acc1[4] = {0,0,0,0};
#pragma unroll 8
    for (int k = 0; k < CH; ++k) {
        float4 wl = *(const float4*)(Wl + k * CH + cg);
        float4 wr = *(const float4*)(Wr + k * CH + cg);
        float m0 = s_mean[nbase][k],   m1 = s_mean[nbase + 1][k];
        float x0 = s_x[nbase][k],      x1 = s_x[nbase + 1][k];
        acc0[0] += m0*wl.x + x0*wr.x;  acc0[1] += m0*wl.y + x0*wr.y;
        acc0[2] += m0*wl.z + x0*wr.z;  acc0[3] += m0*wl.w + x0*wr.w;
        acc1[0] += m1*wl.x + x1*wr.x;  acc1[1] += m1*wl.y + x1*wr.y;
        acc1[2] += m1*wl.z + x1*wr.z;  acc1[3] += m1*wl.w + x1*wr.w;
    }
    float4 bb = *(const float4*)(b + cg);
    int n0 = node0 + nbase, n1 = n0 + 1;
    if (n0 < n_nodes) {
        float4 o = { fmaxf(acc0[0]+bb.x,0.f), fmaxf(acc0[1]+bb.y,0.f),
                     fmaxf(acc0[2]+bb.z,0.f), fmaxf(acc0[3]+bb.w,0.f) };
        *(float4*)(out + (long long)n0 * CH + cg) = o;
    }
    if (n1 < n_nodes) {
        float4 o = { fmaxf(acc1[0]+bb.x,0.f), fmaxf(acc1[1]+bb.y,0.f),
                     fmaxf(acc1[2]+bb.z,0.f), fmaxf(acc1[3]+bb.w,0.f) };
        *(float4*)(out + (long long)n1 * CH + cg) = o;
    }
}

extern "C" void kernel_launch(void* const* d_in, const int* in_sizes, int n_in,
                              void* d_out, int out_size, void* d_ws, size_t ws_size,
                              hipStream_t stream)
{
    const float* x     = (const float*)d_in[0];
    const void*  edges = d_in[1];
    const float* Wl    = (const float*)d_in[2];
    const float* Wr    = (const float*)d_in[3];
    const float* b     = (const float*)d_in[4];
    float*       out   = (float*)d_out;

    const int n_nodes = in_sizes[0] / CH;
    const int n_edges = in_sizes[1] / 2;

    char* ws = (char*)d_ws;
    const size_t ints_n = (size_t)n_nodes * sizeof(int);
    const int    nscan  = (n_nodes + SC_T * SC_I - 1) / (SC_T * SC_I);
    const size_t need   = 3 * ints_n
                        + 1024 * sizeof(int)
                        + 64
                        + (size_t)n_edges * sizeof(int);

    if (ws_size >= need && nscan <= SC_T) {
        int* deg    = (int*)ws;
        int* offs   = (int*)(ws + ints_n);
        int* cursor = (int*)(ws + 2 * ints_n);
        int* bsums  = (int*)(ws + 3 * ints_n);
        int* flag   = (int*)(ws + 3 * ints_n + 1024 * sizeof(int));
        int* sorted = (int*)(ws + 3 * ints_n + 1024 * sizeof(int) + 64);

        hipMemsetAsync(deg, 0, ints_n, stream);
        detect_i64<<<1, 1, 0, stream>>>((const int*)edges, flag);

        const int eb = (n_edges + 255) / 256;
        hist_kernel<<<eb, 256, 0, stream>>>(edges, flag, deg, n_edges);
        scan_blocks<<<nscan, SC_T, 0, stream>>>(deg, offs, bsums, n_nodes);
        scan_totals<<<1, SC_T, 0, stream>>>(bsums, nscan);
        fixup_kernel<<<(n_nodes + 255) / 256, 256, 0, stream>>>(offs, bsums, cursor, n_nodes);
        sort_kernel<<<eb, 256, 0, stream>>>(edges, flag, cursor, sorted, n_edges);

        const int ob = (n_nodes + NB - 1) / NB;
        fused_kernel<<<ob, 256, 0, stream>>>(x, sorted, deg, offs, Wl, Wr, b, out, n_nodes);
    } else {
        float* agg = out;
        float* cnt = (float*)ws;
        int*   flag = (int*)(ws + ints_n);
        hipMemsetAsync(agg, 0, (size_t)n_nodes * CH * sizeof(float), stream);
        hipMemsetAsync(cnt, 0, ints_n, stream);
        detect_i64<<<1, 1, 0, stream>>>((const int*)edges, flag);
        scatter_kernel<<<(n_edges + 3) / 4, 256, 0, stream>>>(x, edges, agg, cnt, flag, n_edges);
        sage_out_kernel<<<(n_nodes + FB_NB - 1) / FB_NB, 256, 0, stream>>>(x, agg, cnt, Wl, Wr, b, out, n_nodes);
    }
}

// Round 4
// 427.236 us; speedup vs baseline: 2.2253x; 1.1578x over previous
//
#include <hip/hip_runtime.h>

#define CH 128
#define NB 64
#define LSTR2 68              // ushorts; 136 B row stride: 8B-aligned, 2-way-free banks
#define FB_NB 16
#define SC_T 256
#define SC_I 8                // 2048 deg entries scanned per block

// ---------------------------------------------------------------------------
// bf16 helpers (RNE)
// ---------------------------------------------------------------------------
__device__ __forceinline__ unsigned bf16rne(float f) {
    unsigned u = __float_as_uint(f);
    return (u + 0x7FFFu + ((u >> 16) & 1u)) >> 16;
}
__device__ __forceinline__ unsigned pack2bf(float lo, float hi) {
    return bf16rne(lo) | (bf16rne(hi) << 16);
}

// ---------------------------------------------------------------------------
// Detect whether edge_index is int64 or int32 on device (odd words all zero
// => int64 with values < 2^31).
// ---------------------------------------------------------------------------
__global__ void detect_i64(const int* __restrict__ ei, int* __restrict__ flag) {
    if (threadIdx.x == 0 && blockIdx.x == 0) {
        int hi_zero = (ei[1] == 0) && (ei[3] == 0) && (ei[5] == 0) && (ei[7] == 0);
        int lo_any  = (ei[0] | ei[2] | ei[4] | ei[6]) != 0;
        *flag = (hi_zero && lo_any) ? 1 : 0;
    }
}

__device__ __forceinline__ int load_dst(const void* edges, int e, int n_edges, int f) {
    const int* p = (const int*)edges;
    return f ? p[2 * (e + n_edges)] : p[e + n_edges];
}
__device__ __forceinline__ int load_src(const void* edges, int e, int f) {
    const int* p = (const int*)edges;
    return f ? p[2 * e] : p[e];
}

// ---------------------------------------------------------------------------
// 1) fused prep: degree histogram (1 edge/thread) + x -> bf16 cast (8 elts/thread)
// ---------------------------------------------------------------------------
__global__ __launch_bounds__(256) void prep_kernel(
    const void* __restrict__ edges, const int* __restrict__ flag,
    int* __restrict__ deg, int n_edges,
    const float* __restrict__ x, ushort* __restrict__ xb, long long n_x)
{
    long long i = (long long)blockIdx.x * 256 + threadIdx.x;
    if (i < n_edges) atomicAdd(&deg[load_dst(edges, (int)i, n_edges, *flag)], 1);
    long long base = i * 8;
    if (base + 8 <= n_x) {
        float4 a = *(const float4*)(x + base);
        float4 c = *(const float4*)(x + base + 4);
        uint4 o;
        o.x = pack2bf(a.x, a.y);
        o.y = pack2bf(a.z, a.w);
        o.z = pack2bf(c.x, c.y);
        o.w = pack2bf(c.z, c.w);
        *(uint4*)(xb + base) = o;
    } else {
        for (long long j = base; j < n_x; ++j) xb[j] = (ushort)bf16rne(x[j]);
    }
}

// ---------------------------------------------------------------------------
// 2) exclusive scan of deg -> offs (3 kernels)
// ---------------------------------------------------------------------------
__global__ __launch_bounds__(SC_T) void scan_blocks(
    const int* __restrict__ deg, int* __restrict__ offs,
    int* __restrict__ bsums, int n)
{
    __shared__ int s_sum[SC_T];
    const int t = threadIdx.x;
    const int base = blockIdx.x * SC_T * SC_I + t * SC_I;
    int v[SC_I];
    int tsum = 0;
#pragma unroll
    for (int i = 0; i < SC_I; ++i) {
        int idx = base + i;
        v[i] = (idx < n) ? deg[idx] : 0;
        tsum += v[i];
    }
    s_sum[t] = tsum;
    __syncthreads();
    for (int off = 1; off < SC_T; off <<= 1) {
        int val = (t >= off) ? s_sum[t - off] : 0;
        __syncthreads();
        s_sum[t] += val;
        __syncthreads();
    }
    int run = s_sum[t] - tsum;
#pragma unroll
    for (int i = 0; i < SC_I; ++i) {
        int idx = base + i;
        if (idx < n) offs[idx] = run;
        run += v[i];
    }
    if (t == SC_T - 1) bsums[blockIdx.x] = s_sum[t];
}

__global__ __launch_bounds__(SC_T) void scan_totals(int* __restrict__ bsums, int nb)
{
    __shared__ int s[SC_T];
    const int t = threadIdx.x;
    int orig = (t < nb) ? bsums[t] : 0;
    s[t] = orig;
    __syncthreads();
    for (int off = 1; off < SC_T; off <<= 1) {
        int val = (t >= off) ? s[t - off] : 0;
        __syncthreads();
        s[t] += val;
        __syncthreads();
    }
    if (t < nb) bsums[t] = s[t] - orig;
}

__global__ __launch_bounds__(256) void fixup_kernel(
    int* __restrict__ offs, const int* __restrict__ bsums,
    int* __restrict__ cursor, int n)
{
    int i = blockIdx.x * 256 + threadIdx.x;
    if (i >= n) return;
    int o = offs[i] + bsums[i / (SC_T * SC_I)];
    offs[i] = o;
    cursor[i] = o;
}

// ---------------------------------------------------------------------------
// 3) scatter src ids into dst-sorted order
// ---------------------------------------------------------------------------
__global__ __launch_bounds__(256) void sort_kernel(
    const void* __restrict__ edges, const int* __restrict__ flag,
    int* __restrict__ cursor, int* __restrict__ sorted, int n_edges)
{
    int e = blockIdx.x * 256 + threadIdx.x;
    if (e >= n_edges) return;
    int f = *flag;
    int d = load_dst(edges, e, n_edges, f);
    int s = load_src(edges, e, f);
    int pos = atomicAdd(&cursor[d], 1);
    sorted[pos] = s;
}

// ---------------------------------------------------------------------------
// 4) fused gather-mean + GEMM, bf16 gather path. 64 nodes/block, 4 blocks/CU.
//    LDS layout: s_[row][node], row r holds channel (r<64 ? 2r : 2(r-64)+1)
//    (lane l accumulates channels 2l,2l+1 from one dword of the bf16 row).
//    GEMM un-permutes via W row index ko = ((k&63)<<1)|(k>>6).
// ---------------------------------------------------------------------------
__global__ __launch_bounds__(256, 4) void fused_bf16_kernel(
    const ushort* __restrict__ xb,
    const int* __restrict__ sorted,
    const int* __restrict__ deg,
    const int* __restrict__ offs,
    const float* __restrict__ Wl,
    const float* __restrict__ Wr,
    const float* __restrict__ b,
    float* __restrict__ out,
    int n_nodes)
{
    __shared__ ushort s_m[CH][LSTR2];
    __shared__ ushort s_v[CH][LSTR2];

    const int node0 = blockIdx.x * NB;
    const int tid   = threadIdx.x;
    const int wave  = tid >> 6;
    const int lane  = tid & 63;

    // ---- gather-mean + x staging: wave handles 16 consecutive nodes ----
    for (int nn = 0; nn < 16; ++nn) {
        int n    = wave * 16 + nn;
        int node = node0 + n;
        float alo = 0.f, ahi = 0.f;
        unsigned xv = 0;
        if (node < n_nodes) {
            xv = *(const unsigned*)(xb + (long long)node * CH + lane * 2);
            int base = offs[node];
            int dg   = deg[node];
            for (int j0 = 0; j0 < dg; j0 += 64) {
                int m  = min(64, dg - j0);
                int sv = (j0 + lane < dg) ? sorted[base + j0 + lane] : 0;
                int jj = 0;
                for (; jj + 16 <= m; jj += 16) {
                    unsigned u[16];
#pragma unroll
                    for (int t = 0; t < 16; ++t) {
                        int s = __shfl(sv, jj + t);
                        u[t] = *(const unsigned*)(xb + (long long)s * CH + lane * 2);
                    }
#pragma unroll
                    for (int t = 0; t < 16; ++t) {
                        alo += __uint_as_float(u[t] << 16);
                        ahi += __uint_as_float(u[t] & 0xFFFF0000u);
                    }
                }
                for (; jj + 4 <= m; jj += 4) {
                    unsigned u[4];
#pragma unroll
                    for (int t = 0; t < 4; ++t) {
                        int s = __shfl(sv, jj + t);
                        u[t] = *(const unsigned*)(xb + (long long)s * CH + lane * 2);
                    }
#pragma unroll
                    for (int t = 0; t < 4; ++t) {
                        alo += __uint_as_float(u[t] << 16);
                        ahi += __uint_as_float(u[t] & 0xFFFF0000u);
                    }
                }
                for (; jj < m; ++jj) {
                    int s = __shfl(sv, jj);
                    unsigned u = *(const unsigned*)(xb + (long long)s * CH + lane * 2);
                    alo += __uint_as_float(u << 16);
                    ahi += __uint_as_float(u & 0xFFFF0000u);
                }
            }
            float inv = 1.0f / fmaxf((float)dg, 1.0f);
            alo *= inv; ahi *= inv;
        }
        s_m[lane][n]      = (ushort)bf16rne(alo);
        s_m[lane + 64][n] = (ushort)bf16rne(ahi);
        s_v[lane][n]      = (ushort)(xv & 0xFFFFu);
        s_v[lane + 64][n] = (ushort)(xv >> 16);
    }
    __syncthreads();

    // ---- GEMM: out = relu(mean @ Wl + x @ Wr + b) ----
    const int cg = (tid & 31) * 4;      // 4 output channels
    const int ng = (tid >> 5) * 8;      // 8 nodes

    float acc[8][4];
#pragma unroll
    for (int u = 0; u < 8; ++u)
#pragma unroll
        for (int j = 0; j < 4; ++j) acc[u][j] = 0.f;

#pragma unroll 4
    for (int k = 0; k < CH; ++k) {
        const int ko = ((k & 63) << 1) | (k >> 6);   // stored row -> channel
        float4 wl = *(const float4*)(Wl + ko * CH + cg);
        float4 wr = *(const float4*)(Wr + ko * CH + cg);
        uint2 m01 = *(const uint2*)&s_m[k][ng];
        uint2 m23 = *(const uint2*)&s_m[k][ng + 4];
        uint2 v01 = *(const uint2*)&s_v[k][ng];
        uint2 v23 = *(const uint2*)&s_v[k][ng + 4];
        float mv[8], vv[8];
        mv[0] = __uint_as_float(m01.x << 16); mv[1] = __uint_as_float(m01.x & 0xFFFF0000u);
        mv[2] = __uint_as_float(m01.y << 16); mv[3] = __uint_as_float(m01.y & 0xFFFF0000u);
        mv[4] = __uint_as_float(m23.x << 16); mv[5] = __uint_as_float(m23.x & 0xFFFF0000u);
        mv[6] = __uint_as_float(m23.y << 16); mv[7] = __uint_as_float(m23.y & 0xFFFF0000u);
        vv[0] = __uint_as_float(v01.x << 16); vv[1] = __uint_as_float(v01.x & 0xFFFF0000u);
        vv[2] = __uint_as_float(v01.y << 16); vv[3] = __uint_as_float(v01.y & 0xFFFF0000u);
        vv[4] = __uint_as_float(v23.x << 16); vv[5] = __uint_as_float(v23.x & 0xFFFF0000u);
        vv[6] = __uint_as_float(v23.y << 16); vv[7] = __uint_as_float(v23.y & 0xFFFF0000u);
#pragma unroll
        for (int u = 0; u < 8; ++u) {
            acc[u][0] += mv[u] * wl.x + vv[u] * wr.x;
            acc[u][1] += mv[u] * wl.y + vv[u] * wr.y;
            acc[u][2] += mv[u] * wl.z + vv[u] * wr.z;
            acc[u][3] += mv[u] * wl.w + vv[u] * wr.w;
        }
    }

    float4 bb = *(const float4*)(b + cg);
#pragma unroll
    for (int u = 0; u < 8; ++u) {
        int node = node0 + ng + u;
        if (node < n_nodes) {
            float4 o;
            o.x = fmaxf(acc[u][0] + bb.x, 0.0f);
            o.y = fmaxf(acc[u][1] + bb.y, 0.0f);
            o.z = fmaxf(acc[u][2] + bb.z, 0.0f);
            o.w = fmaxf(acc[u][3] + bb.w, 0.0f);
            *(float4*)(out + (long long)node * CH + cg) = o;
        }
    }
}

// ---------------------------------------------------------------------------
// Path B: f32 fused kernel (round-3) for smaller workspaces.
// ---------------------------------------------------------------------------
#define LPAD 4
#define LSTR (NB + LPAD)

__global__ __launch_bounds__(256) void fused_kernel(
    const float* __restrict__ x,
    const int* __restrict__ sorted,
    const int* __restrict__ deg,
    const int* __restrict__ offs,
    const float* __restrict__ Wl,
    const float* __restrict__ Wr,
    const float* __restrict__ b,
    float* __restrict__ out,
    int n_nodes)
{
    __shared__ float s_m[CH][LSTR];
    __shared__ float s_v[CH][LSTR];

    const int node0 = blockIdx.x * NB;
    const int tid   = threadIdx.x;
    const int wave  = tid >> 6;
    const int lane  = tid & 63;

    for (int nn = 0; nn < 16; ++nn) {
        int n    = wave * 16 + nn;
        int node = node0 + n;
        float a0 = 0.f, a1 = 0.f, x0 = 0.f, x1 = 0.f;
        if (node < n_nodes) {
            const float* xr = x + (long long)node * CH;
            x0 = xr[lane];
            x1 = xr[lane + 64];
            int base = offs[node];
            int dg   = deg[node];
            for (int j0 = 0; j0 < dg; j0 += 64) {
                int m  = min(64, dg - j0);
                int sv = (j0 + lane < dg) ? sorted[base + j0 + lane] : 0;
                int jj = 0;
                for (; jj + 8 <= m; jj += 8) {
                    float v0[8], v1[8];
#pragma unroll
                    for (int u = 0; u < 8; ++u) {
                        int s = __shfl(sv, jj + u);
                        const float* p = x + (long long)s * CH;
                        v0[u] = p[lane];
                        v1[u] = p[lane + 64];
                    }
#pragma unroll
                    for (int u = 0; u < 8; ++u) { a0 += v0[u]; a1 += v1[u]; }
                }
                for (; jj < m; ++jj) {
                    int s = __shfl(sv, jj);
                    const float* p = x + (long long)s * CH;
                    a0 += p[lane];
                    a1 += p[lane + 64];
                }
            }
            float inv = 1.0f / fmaxf((float)dg, 1.0f);
            a0 *= inv; a1 *= inv;
        }
        s_m[lane][n]      = a0;
        s_m[lane + 64][n] = a1;
        s_v[lane][n]      = x0;
        s_v[lane + 64][n] = x1;
    }
    __syncthreads();

    const int cg = (tid & 31) * 4;
    const int ng = (tid >> 5) * 8;

    float acc[8][4];
#pragma unroll
    for (int u = 0; u < 8; ++u)
#pragma unroll
        for (int j = 0; j < 4; ++j) acc[u][j] = 0.f;

#pragma unroll 4
    for (int k = 0; k < CH; ++k) {
        const float* mr = &s_m[k][ng];
        const float* vr = &s_v[k][ng];
        float4 wl = *(const float4*)(Wl + k * CH + cg);
        float4 wr = *(const float4*)(Wr + k * CH + cg);
#pragma unroll
        for (int u = 0; u < 8; ++u) {
            float m  = mr[u];
            float xv = vr[u];
            acc[u][0] += m * wl.x + xv * wr.x;
            acc[u][1] += m * wl.y + xv * wr.y;
            acc[u][2] += m * wl.z + xv * wr.z;
            acc[u][3] += m * wl.w + xv * wr.w;
        }
    }

    float4 bb = *(const float4*)(b + cg);
#pragma unroll
    for (int u = 0; u < 8; ++u) {
        int node = node0 + ng + u;
        if (node < n_nodes) {
            float4 o;
            o.x = fmaxf(acc[u][0] + bb.x, 0.0f);
            o.y = fmaxf(acc[u][1] + bb.y, 0.0f);
            o.z = fmaxf(acc[u][2] + bb.z, 0.0f);
            o.w = fmaxf(acc[u][3] + bb.w, 0.0f);
            *(float4*)(out + (long long)node * CH + cg) = o;
        }
    }
}

__global__ __launch_bounds__(256) void hist_kernel(
    const void* __restrict__ edges, const int* __restrict__ flag,
    int* __restrict__ deg, int n_edges)
{
    int e = blockIdx.x * 256 + threadIdx.x;
    if (e >= n_edges) return;
    atomicAdd(&deg[load_dst(edges, e, n_edges, *flag)], 1);
}

// ---------------------------------------------------------------------------
// Path C: atomic fallback (tiny workspace).
// ---------------------------------------------------------------------------
__global__ __launch_bounds__(256) void scatter_kernel(
    const float* __restrict__ x, const void* __restrict__ edges,
    float* __restrict__ agg, float* __restrict__ cnt,
    const int* __restrict__ flag, int n_edges)
{
    int e = blockIdx.x * 4 + (threadIdx.x >> 6);
    if (e >= n_edges) return;
    int lane = threadIdx.x & 63;
    int f = *flag;
    long long s = load_src(edges, e, f);
    long long d = load_dst(edges, e, n_edges, f);
    const float* xs = x + s * (long long)CH;
    float*       ad = agg + d * (long long)CH;
    unsafeAtomicAdd(ad + lane,      xs[lane]);
    unsafeAtomicAdd(ad + lane + 64, xs[lane + 64]);
    if (lane == 0) unsafeAtomicAdd(cnt + d, 1.0f);
}

__global__ __launch_bounds__(256) void sage_out_kernel(
    const float* __restrict__ x, const float* agg, const float* __restrict__ cnt,
    const float* __restrict__ Wl, const float* __restrict__ Wr,
    const float* __restrict__ b, float* out, int n_nodes)
{
    __shared__ float s_mean[FB_NB][CH];
    __shared__ float s_x[FB_NB][CH];
    const int node0 = blockIdx.x * FB_NB;
    const int tid   = threadIdx.x;
    for (int i = tid; i < FB_NB * CH; i += 256) {
        int n = i >> 7, c = i & (CH - 1);
        int node = node0 + n;
        float a = 0.0f, xv = 0.0f, inv = 1.0f;
        if (node < n_nodes) {
            inv = 1.0f / fmaxf(cnt[node], 1.0f);
            a  = agg[(long long)node * CH + c];
            xv = x[(long long)node * CH + c];
        }
        s_mean[n][c] = a * inv;
        s_x[n][c]    = xv;
    }
    __syncthreads();
    const int cg = (tid & 31) * 4, nbase = (tid >> 5) * 2;
    float acc0[4] = {0,0,0,0}, acc1[4] = {0,0,0,0};
#pragma unroll 8
    for (int k = 0; k < CH; ++k) {
        float4 wl = *(const float4*)(Wl + k * CH + cg);
        float4 wr = *(const float4*)(Wr + k * CH + cg);
        float m0 = s_mean[nbase][k],   m1 = s_mean[nbase + 1][k];
        float x0 = s_x[nbase][k],      x1 = s_x[nbase + 1][k];
        acc0[0] += m0*wl.x + x0*wr.x;  acc0[1] += m0*wl.y + x0*wr.y;
        acc0[2] += m0*wl.z + x0*wr.z;  acc0[3] += m0*wl.w + x0*wr.w;
        acc1[0] += m1*wl.x + x1*wr.x;  acc1[1] += m1*wl.y + x1*wr.y;
        acc1[2] += m1*wl.z + x1*wr.z;  acc1[3] += m1*wl.w + x1*wr.w;
    }
    float4 bb = *(const float4*)(b + cg);
    int n0 = node0 + nbase, n1 = n0 + 1;
    if (n0 < n_nodes) {
        float4 o = { fmaxf(acc0[0]+bb.x,0.f), fmaxf(acc0[1]+bb.y,0.f),
                     fmaxf(acc0[2]+bb.z,0.f), fmaxf(acc0[3]+bb.w,0.f) };
        *(float4*)(out + (long long)n0 * CH + cg) = o;
    }
    if (n1 < n_nodes) {
        float4 o = { fmaxf(acc1[0]+bb.x,0.f), fmaxf(acc1[1]+bb.y,0.f),
                     fmaxf(acc1[2]+bb.z,0.f), fmaxf(acc1[3]+bb.w,0.f) };
        *(float4*)(out + (long long)n1 * CH + cg) = o;
    }
}

extern "C" void kernel_launch(void* const* d_in, const int* in_sizes, int n_in,
                              void* d_out, int out_size, void* d_ws, size_t ws_size,
                              hipStream_t stream)
{
    const float* x     = (const float*)d_in[0];
    const void*  edges = d_in[1];
    const float* Wl    = (const float*)d_in[2];
    const float* Wr    = (const float*)d_in[3];
    const float* b     = (const float*)d_in[4];
    float*       out   = (float*)d_out;

    const int n_nodes = in_sizes[0] / CH;
    const int n_edges = in_sizes[1] / 2;
    const long long n_x = (long long)n_nodes * CH;

    char* ws = (char*)d_ws;
    const size_t ints_n = (size_t)n_nodes * sizeof(int);
    const int    nscan  = (n_nodes + SC_T * SC_I - 1) / (SC_T * SC_I);
    const size_t sort_need = 3 * ints_n + 1024 * sizeof(int) + 64
                           + (size_t)n_edges * sizeof(int);
    const size_t xb_off    = (sort_need + 255) & ~(size_t)255;
    const size_t full_need = xb_off + (size_t)n_x * sizeof(ushort);

    if (ws_size >= sort_need && nscan <= SC_T) {
        int* deg    = (int*)ws;
        int* offs   = (int*)(ws + ints_n);
        int* cursor = (int*)(ws + 2 * ints_n);
        int* bsums  = (int*)(ws + 3 * ints_n);
        int* flag   = (int*)(ws + 3 * ints_n + 1024 * sizeof(int));
        int* sorted = (int*)(ws + 3 * ints_n + 1024 * sizeof(int) + 64);
        const bool bf16_path = (ws_size >= full_need);
        ushort* xb = (ushort*)(ws + xb_off);

        hipMemsetAsync(deg, 0, ints_n, stream);
        detect_i64<<<1, 1, 0, stream>>>((const int*)edges, flag);

        const int eb = (n_edges + 255) / 256;
        if (bf16_path) {
            const long long cast_blocks = (n_x + 2047) / 2048;
            const int pb = (int)((cast_blocks > eb) ? cast_blocks : eb);
            prep_kernel<<<pb, 256, 0, stream>>>(edges, flag, deg, n_edges, x, xb, n_x);
        } else {
            hist_kernel<<<eb, 256, 0, stream>>>(edges, flag, deg, n_edges);
        }
        scan_blocks<<<nscan, SC_T, 0, stream>>>(deg, offs, bsums, n_nodes);
        scan_totals<<<1, SC_T, 0, stream>>>(bsums, nscan);
        fixup_kernel<<<(n_nodes + 255) / 256, 256, 0, stream>>>(offs, bsums, cursor, n_nodes);
        sort_kernel<<<eb, 256, 0, stream>>>(edges, flag, cursor, sorted, n_edges);

        const int ob = (n_nodes + NB - 1) / NB;
        if (bf16_path) {
            fused_bf16_kernel<<<ob, 256, 0, stream>>>(xb, sorted, deg, offs, Wl, Wr, b, out, n_nodes);
        } else {
            fused_kernel<<<ob, 256, 0, stream>>>(x, sorted, deg, offs, Wl, Wr, b, out, n_nodes);
        }
    } else {
        float* agg = out;
        float* cnt = (float*)ws;
        int*   flag = (int*)(ws + ints_n);
        hipMemsetAsync(agg, 0, (size_t)n_nodes * CH * sizeof(float), stream);
        hipMemsetAsync(cnt, 0, ints_n, stream);
        detect_i64<<<1, 1, 0, stream>>>((const int*)edges, flag);
        scatter_kernel<<<(n_edges + 3) / 4, 256, 0, stream>>>(x, edges, agg, cnt, flag, n_edges);
        sage_out_kernel<<<(n_nodes + FB_NB - 1) / FB_NB, 256, 0, stream>>>(x, agg, cnt, Wl, Wr, b, out, n_nodes);
    }
}

// Round 5
// 394.371 us; speedup vs baseline: 2.4108x; 1.0833x over previous
//
#include <hip/hip_runtime.h>

#define CH 128
#define NB 64
#define LSTR2 68              // ushorts; 136 B row stride: 8B-aligned, 2-way-free banks
#define FB_NB 16
#define SC_T 256
#define SC_I 8                // 2048 deg entries scanned per block

// ---------------------------------------------------------------------------
// bf16 helpers (RNE)
// ---------------------------------------------------------------------------
__device__ __forceinline__ unsigned bf16rne(float f) {
    unsigned u = __float_as_uint(f);
    return (u + 0x7FFFu + ((u >> 16) & 1u)) >> 16;
}
__device__ __forceinline__ unsigned pack2bf(float lo, float hi) {
    return bf16rne(lo) | (bf16rne(hi) << 16);
}

// ---------------------------------------------------------------------------
// int64-vs-int32 edge_index detection, inlined per-thread (broadcast loads of
// the first 8 words; for int64 data < 2^31 every odd word is 0).
// ---------------------------------------------------------------------------
__device__ __forceinline__ int detect_f(const void* edges) {
    const int* ei = (const int*)edges;
    int hi_zero = (ei[1] == 0) & (ei[3] == 0) & (ei[5] == 0) & (ei[7] == 0);
    int lo_any  = (ei[0] | ei[2] | ei[4] | ei[6]) != 0;
    return hi_zero & lo_any;
}

__device__ __forceinline__ int load_dst(const void* edges, int e, int n_edges, int f) {
    const int* p = (const int*)edges;
    return f ? p[2 * (e + n_edges)] : p[e + n_edges];
}
__device__ __forceinline__ int load_src(const void* edges, int e, int f) {
    const int* p = (const int*)edges;
    return f ? p[2 * e] : p[e];
}

// ---------------------------------------------------------------------------
// 1) fused prep: degree histogram (1 edge/thread) + x -> bf16 cast (8 elts/thread)
// ---------------------------------------------------------------------------
__global__ __launch_bounds__(256) void prep_kernel(
    const void* __restrict__ edges,
    int* __restrict__ deg, int n_edges,
    const float* __restrict__ x, ushort* __restrict__ xb, long long n_x)
{
    const int f = detect_f(edges);
    long long i = (long long)blockIdx.x * 256 + threadIdx.x;
    if (i < n_edges) atomicAdd(&deg[load_dst(edges, (int)i, n_edges, f)], 1);
    long long base = i * 8;
    if (base + 8 <= n_x) {
        float4 a = *(const float4*)(x + base);
        float4 c = *(const float4*)(x + base + 4);
        uint4 o;
        o.x = pack2bf(a.x, a.y);
        o.y = pack2bf(a.z, a.w);
        o.z = pack2bf(c.x, c.y);
        o.w = pack2bf(c.z, c.w);
        *(uint4*)(xb + base) = o;
    } else {
        for (long long j = base; j < n_x; ++j) xb[j] = (ushort)bf16rne(x[j]);
    }
}

// ---------------------------------------------------------------------------
// 2) exclusive scan of deg -> offs (scan_blocks + merged fixup)
// ---------------------------------------------------------------------------
__global__ __launch_bounds__(SC_T) void scan_blocks(
    const int* __restrict__ deg, int* __restrict__ offs,
    int* __restrict__ bsums, int n)
{
    __shared__ int s_sum[SC_T];
    const int t = threadIdx.x;
    const int base = blockIdx.x * SC_T * SC_I + t * SC_I;
    int v[SC_I];
    int tsum = 0;
#pragma unroll
    for (int i = 0; i < SC_I; ++i) {
        int idx = base + i;
        v[i] = (idx < n) ? deg[idx] : 0;
        tsum += v[i];
    }
    s_sum[t] = tsum;
    __syncthreads();
    for (int off = 1; off < SC_T; off <<= 1) {
        int val = (t >= off) ? s_sum[t - off] : 0;
        __syncthreads();
        s_sum[t] += val;
        __syncthreads();
    }
    int run = s_sum[t] - tsum;
#pragma unroll
    for (int i = 0; i < SC_I; ++i) {
        int idx = base + i;
        if (idx < n) offs[idx] = run;
        run += v[i];
    }
    if (t == SC_T - 1) bsums[blockIdx.x] = s_sum[t];
}

// merged: adds bsums prefix (<=~50 broadcast loads) and inits cursor
__global__ __launch_bounds__(256) void fixup_kernel(
    int* __restrict__ offs, const int* __restrict__ bsums,
    int* __restrict__ cursor, int n)
{
    int i = blockIdx.x * 256 + threadIdx.x;
    if (i >= n) return;
    int bucket = i / (SC_T * SC_I);
    int add = 0;
    for (int j = 0; j < bucket; ++j) add += bsums[j];
    int o = offs[i] + add;
    offs[i] = o;
    cursor[i] = o;
}

// ---------------------------------------------------------------------------
// 3) scatter src ids into dst-sorted order
// ---------------------------------------------------------------------------
__global__ __launch_bounds__(256) void sort_kernel(
    const void* __restrict__ edges,
    int* __restrict__ cursor, int* __restrict__ sorted, int n_edges)
{
    const int f = detect_f(edges);
    int e = blockIdx.x * 256 + threadIdx.x;
    if (e >= n_edges) return;
    int d = load_dst(edges, e, n_edges, f);
    int s = load_src(edges, e, f);
    int pos = atomicAdd(&cursor[d], 1);
    sorted[pos] = s;
}

// ---------------------------------------------------------------------------
// 4) fused gather-mean + GEMM, bf16, software-pipelined flat-stream gather.
//    Wave processes its 16 nodes' contiguous edge range as one stream of
//    16-edge double-buffered batches; node boundaries flushed inline.
// ---------------------------------------------------------------------------
__global__ __launch_bounds__(256, 4) void fused_bf16_kernel(
    const ushort* __restrict__ xb,
    const int* __restrict__ sorted,
    const int* __restrict__ deg,
    const int* __restrict__ offs,
    const float* __restrict__ Wl,
    const float* __restrict__ Wr,
    const float* __restrict__ b,
    float* __restrict__ out,
    int n_nodes, int nE)
{
    __shared__ ushort s_m[CH][LSTR2];
    __shared__ ushort s_v[CH][LSTR2];

    const int node0 = blockIdx.x * NB;
    const int tid   = threadIdx.x;
    const int wave  = tid >> 6;
    const int lane  = tid & 63;
    const int first = node0 + wave * 16;

    if (first < n_nodes) {
        const int nval = min(16, n_nodes - first);

        // ---- own-x staging (coalesced) ----
        unsigned xv[16];
#pragma unroll
        for (int nn = 0; nn < 16; ++nn) {
            int node = min(first + nn, n_nodes - 1);
            xv[nn] = *(const unsigned*)(xb + (size_t)node * CH + lane * 2);
        }
#pragma unroll
        for (int nn = 0; nn < 16; ++nn) {
            s_v[lane][wave * 16 + nn]      = (ushort)(xv[nn] & 0xFFFFu);
            s_v[lane + 64][wave * 16 + nn] = (ushort)(xv[nn] >> 16);
        }

        // ---- flat-stream gather over [base0, e_end) ----
        const int base0 = offs[first];
        const int e_end = (first + nval < n_nodes) ? offs[first + nval] : nE;
        const int Ew      = e_end - base0;
        const int nb_full = Ew >> 4;
        const int rem     = Ew & 15;

        int   nstored = 0;
        int   dcur    = deg[first];
        int   cur_end = base0 + dcur;
        float alo = 0.f, ahi = 0.f;

        int sv_cur = 0, sv_nxt = 0;
        if (Ew > 0) sv_cur = sorted[min(base0 + lane, nE - 1)];

        auto flushfn = [&](int ii) {
            while (ii == cur_end && nstored < nval) {
                float sc  = 1.0f / fmaxf((float)dcur, 1.0f);
                int   col = wave * 16 + nstored;
                s_m[lane][col]      = (ushort)bf16rne(alo * sc);
                s_m[lane + 64][col] = (ushort)bf16rne(ahi * sc);
                alo = 0.f; ahi = 0.f;
                ++nstored;
                if (nstored < nval) { dcur = deg[first + nstored]; cur_end += dcur; }
            }
        };
        auto issue = [&](unsigned (&U)[16], int bb) {
            if ((bb & 3) == 0) {
                if (bb > 0) sv_cur = sv_nxt;
                int c = (bb >> 2) + 1;
                if (c * 64 < Ew) sv_nxt = sorted[min(base0 + c * 64 + lane, nE - 1)];
            }
            int q = (bb & 3) * 16;
#pragma unroll
            for (int t = 0; t < 16; ++t) {
                int s = __shfl(sv_cur, q + t);
                U[t] = *(const unsigned*)(xb + (size_t)s * CH + lane * 2);
            }
        };
        auto accum = [&](unsigned (&U)[16], int bb) {
            int i0 = base0 + bb * 16;
#pragma unroll
            for (int t = 0; t < 16; ++t) {
                flushfn(i0 + t);
                alo += __uint_as_float(U[t] << 16);
                ahi += __uint_as_float(U[t] & 0xFFFF0000u);
            }
        };

        unsigned uA[16], uB[16];
        if (nb_full > 0) issue(uA, 0);
        int bI = 0;
        while (bI < nb_full) {
            if (bI + 1 < nb_full) issue(uB, bI + 1);
            accum(uA, bI);
            ++bI;
            if (bI >= nb_full) break;
            if (bI + 1 < nb_full) issue(uA, bI + 1);
            accum(uB, bI);
            ++bI;
        }

        if (rem > 0) {
            if (nb_full > 0 && (nb_full & 3) == 0) sv_cur = sv_nxt;
            int q = (nb_full & 3) * 16;
            for (int t = 0; t < rem; ++t) {
                int i = base0 + nb_full * 16 + t;
                int s = __shfl(sv_cur, q + t);
                unsigned u = *(const unsigned*)(xb + (size_t)s * CH + lane * 2);
                flushfn(i);
                alo += __uint_as_float(u << 16);
                ahi += __uint_as_float(u & 0xFFFF0000u);
            }
        }

        // final flush (current node + trailing zero-degree nodes)
        while (nstored < nval) {
            float sc  = 1.0f / fmaxf((float)dcur, 1.0f);
            int   col = wave * 16 + nstored;
            s_m[lane][col]      = (ushort)bf16rne(alo * sc);
            s_m[lane + 64][col] = (ushort)bf16rne(ahi * sc);
            alo = 0.f; ahi = 0.f;
            ++nstored;
            if (nstored < nval) dcur = deg[first + nstored];
        }
    }
    __syncthreads();

    // ---- GEMM: out = relu(mean @ Wl + x @ Wr + b) ----
    const int cg = (tid & 31) * 4;      // 4 output channels
    const int ng = (tid >> 5) * 8;      // 8 nodes

    float acc[8][4];
#pragma unroll
    for (int u = 0; u < 8; ++u)
#pragma unroll
        for (int j = 0; j < 4; ++j) acc[u][j] = 0.f;

#pragma unroll 4
    for (int k = 0; k < CH; ++k) {
        const int ko = ((k & 63) << 1) | (k >> 6);   // stored row -> channel
        float4 wl = *(const float4*)(Wl + ko * CH + cg);
        float4 wr = *(const float4*)(Wr + ko * CH + cg);
        uint2 m01 = *(const uint2*)&s_m[k][ng];
        uint2 m23 = *(const uint2*)&s_m[k][ng + 4];
        uint2 v01 = *(const uint2*)&s_v[k][ng];
        uint2 v23 = *(const uint2*)&s_v[k][ng + 4];
        float mv[8], vv[8];
        mv[0] = __uint_as_float(m01.x << 16); mv[1] = __uint_as_float(m01.x & 0xFFFF0000u);
        mv[2] = __uint_as_float(m01.y << 16); mv[3] = __uint_as_float(m01.y & 0xFFFF0000u);
        mv[4] = __uint_as_float(m23.x << 16); mv[5] = __uint_as_float(m23.x & 0xFFFF0000u);
        mv[6] = __uint_as_float(m23.y << 16); mv[7] = __uint_as_float(m23.y & 0xFFFF0000u);
        vv[0] = __uint_as_float(v01.x << 16); vv[1] = __uint_as_float(v01.x & 0xFFFF0000u);
        vv[2] = __uint_as_float(v01.y << 16); vv[3] = __uint_as_float(v01.y & 0xFFFF0000u);
        vv[4] = __uint_as_float(v23.x << 16); vv[5] = __uint_as_float(v23.x & 0xFFFF0000u);
        vv[6] = __uint_as_float(v23.y << 16); vv[7] = __uint_as_float(v23.y & 0xFFFF0000u);
#pragma unroll
        for (int u = 0; u < 8; ++u) {
            acc[u][0] += mv[u] * wl.x + vv[u] * wr.x;
            acc[u][1] += mv[u] * wl.y + vv[u] * wr.y;
            acc[u][2] += mv[u] * wl.z + vv[u] * wr.z;
            acc[u][3] += mv[u] * wl.w + vv[u] * wr.w;
        }
    }

    float4 bb = *(const float4*)(b + cg);
#pragma unroll
    for (int u = 0; u < 8; ++u) {
        int node = node0 + ng + u;
        if (node < n_nodes) {
            float4 o;
            o.x = fmaxf(acc[u][0] + bb.x, 0.0f);
            o.y = fmaxf(acc[u][1] + bb.y, 0.0f);
            o.z = fmaxf(acc[u][2] + bb.z, 0.0f);
            o.w = fmaxf(acc[u][3] + bb.w, 0.0f);
            *(float4*)(out + (long long)node * CH + cg) = o;
        }
    }
}

// ---------------------------------------------------------------------------
// Path B: f32 fused kernel for smaller workspaces.
// ---------------------------------------------------------------------------
#define LPAD 4
#define LSTR (NB + LPAD)

__global__ __launch_bounds__(256) void fused_kernel(
    const float* __restrict__ x,
    const int* __restrict__ sorted,
    const int* __restrict__ deg,
    const int* __restrict__ offs,
    const float* __restrict__ Wl,
    const float* __restrict__ Wr,
    const float* __restrict__ b,
    float* __restrict__ out,
    int n_nodes)
{
    __shared__ float s_m[CH][LSTR];
    __shared__ float s_v[CH][LSTR];

    const int node0 = blockIdx.x * NB;
    const int tid   = threadIdx.x;
    const int wave  = tid >> 6;
    const int lane  = tid & 63;

    for (int nn = 0; nn < 16; ++nn) {
        int n    = wave * 16 + nn;
        int node = node0 + n;
        float a0 = 0.f, a1 = 0.f, x0 = 0.f, x1 = 0.f;
        if (node < n_nodes) {
            const float* xr = x + (long long)node * CH;
            x0 = xr[lane];
            x1 = xr[lane + 64];
            int base = offs[node];
            int dg   = deg[node];
            for (int j0 = 0; j0 < dg; j0 += 64) {
                int m  = min(64, dg - j0);
                int sv = (j0 + lane < dg) ? sorted[base + j0 + lane] : 0;
                int jj = 0;
                for (; jj + 8 <= m; jj += 8) {
                    float v0[8], v1[8];
#pragma unroll
                    for (int u = 0; u < 8; ++u) {
                        int s = __shfl(sv, jj + u);
                        const float* p = x + (long long)s * CH;
                        v0[u] = p[lane];
                        v1[u] = p[lane + 64];
                    }
#pragma unroll
                    for (int u = 0; u < 8; ++u) { a0 += v0[u]; a1 += v1[u]; }
                }
                for (; jj < m; ++jj) {
                    int s = __shfl(sv, jj);
                    const float* p = x + (long long)s * CH;
                    a0 += p[lane];
                    a1 += p[lane + 64];
                }
            }
            float inv = 1.0f / fmaxf((float)dg, 1.0f);
            a0 *= inv; a1 *= inv;
        }
        s_m[lane][n]      = a0;
        s_m[lane + 64][n] = a1;
        s_v[lane][n]      = x0;
        s_v[lane + 64][n] = x1;
    }
    __syncthreads();

    const int cg = (tid & 31) * 4;
    const int ng = (tid >> 5) * 8;

    float acc[8][4];
#pragma unroll
    for (int u = 0; u < 8; ++u)
#pragma unroll
        for (int j = 0; j < 4; ++j) acc[u][j] = 0.f;

#pragma unroll 4
    for (int k = 0; k < CH; ++k) {
        const float* mr = &s_m[k][ng];
        const float* vr = &s_v[k][ng];
        float4 wl = *(const float4*)(Wl + k * CH + cg);
        float4 wr = *(const float4*)(Wr + k * CH + cg);
#pragma unroll
        for (int u = 0; u < 8; ++u) {
            float m  = mr[u];
            float xv = vr[u];
            acc[u][0] += m * wl.x + xv * wr.x;
            acc[u][1] += m * wl.y + xv * wr.y;
            acc[u][2] += m * wl.z + xv * wr.z;
            acc[u][3] += m * wl.w + xv * wr.w;
        }
    }

    float4 bb = *(const float4*)(b + cg);
#pragma unroll
    for (int u = 0; u < 8; ++u) {
        int node = node0 + ng + u;
        if (node < n_nodes) {
            float4 o;
            o.x = fmaxf(acc[u][0] + bb.x, 0.0f);
            o.y = fmaxf(acc[u][1] + bb.y, 0.0f);
            o.z = fmaxf(acc[u][2] + bb.z, 0.0f);
            o.w = fmaxf(acc[u][3] + bb.w, 0.0f);
            *(float4*)(out + (long long)node * CH + cg) = o;
        }
    }
}

__global__ __launch_bounds__(256) void hist_kernel(
    const void* __restrict__ edges,
    int* __restrict__ deg, int n_edges)
{
    const int f = detect_f(edges);
    int e = blockIdx.x * 256 + threadIdx.x;
    if (e >= n_edges) return;
    atomicAdd(&deg[load_dst(edges, e, n_edges, f)], 1);
}

// ---------------------------------------------------------------------------
// Path C: atomic fallback (tiny workspace).
// ---------------------------------------------------------------------------
__global__ __launch_bounds__(256) void scatter_kernel(
    const float* __restrict__ x, const void* __restrict__ edges,
    float* __restrict__ agg, float* __restrict__ cnt, int n_edges)
{
    const int f = detect_f(edges);
    int e = blockIdx.x * 4 + (threadIdx.x >> 6);
    if (e >= n_edges) return;
    int lane = threadIdx.x & 63;
    long long s = load_src(edges, e, f);
    long long d = load_dst(edges, e, n_edges, f);
    const float* xs = x + s * (long long)CH;
    float*       ad = agg + d * (long long)CH;
    unsafeAtomicAdd(ad + lane,      xs[lane]);
    unsafeAtomicAdd(ad + lane + 64, xs[lane + 64]);
    if (lane == 0) unsafeAtomicAdd(cnt + d, 1.0f);
}

__global__ __launch_bounds__(256) void sage_out_kernel(
    const float* __restrict__ x, const float* agg, const float* __restrict__ cnt,
    const float* __restrict__ Wl, const float* __restrict__ Wr,
    const float* __restrict__ b, float* out, int n_nodes)
{
    __shared__ float s_mean[FB_NB][CH];
    __shared__ float s_x[FB_NB][CH];
    const int node0 = blockIdx.x * FB_NB;
    const int tid   = threadIdx.x;
    for (int i = tid; i < FB_NB * CH; i += 256) {
        int n = i >> 7, c = i & (CH - 1);
        int node = node0 + n;
        float a = 0.0f, xv = 0.0f, inv = 1.0f;
        if (node < n_nodes) {
            inv = 1.0f / fmaxf(cnt[node], 1.0f);
            a  = agg[(long long)node * CH + c];
            xv = x[(long long)node * CH + c];
        }
        s_mean[n][c] = a * inv;
        s_x[n][c]    = xv;
    }
    __syncthreads();
    const int cg = (tid & 31) * 4, nbase = (tid >> 5) * 2;
    float acc0[4] = {0,0,0,0}, acc1[4] = {0,0,0,0};
#pragma unroll 8
    for (int k = 0; k < CH; ++k) {
        float4 wl = *(const float4*)(Wl + k * CH + cg);
        float4 wr = *(const float4*)(Wr + k * CH + cg);
        float m0 = s_mean[nbase][k],   m1 = s_mean[nbase + 1][k];
        float x0 = s_x[nbase][k],      x1 = s_x[nbase + 1][k];
        acc0[0] += m0*wl.x + x0*wr.x;  acc0[1] += m0*wl.y + x0*wr.y;
        acc0[2] += m0*wl.z + x0*wr.z;  acc0[3] += m0*wl.w + x0*wr.w;
        acc1[0] += m1*wl.x + x1*wr.x;  acc1[1] += m1*wl.y + x1*wr.y;
        acc1[2] += m1*wl.z + x1*wr.z;  acc1[3] += m1*wl.w + x1*wr.w;
    }
    float4 bb = *(const float4*)(b + cg);
    int n0 = node0 + nbase, n1 = n0 + 1;
    if (n0 < n_nodes) {
        float4 o = { fmaxf(acc0[0]+bb.x,0.f), fmaxf(acc0[1]+bb.y,0.f),
                     fmaxf(acc0[2]+bb.z,0.f), fmaxf(acc0[3]+bb.w,0.f) };
        *(float4*)(out + (long long)n0 * CH + cg) = o;
    }
    if (n1 < n_nodes) {
        float4 o = { fmaxf(acc1[0]+bb.x,0.f), fmaxf(acc1[1]+bb.y,0.f),
                     fmaxf(acc1[2]+bb.z,0.f), fmaxf(acc1[3]+bb.w,0.f) };
        *(float4*)(out + (long long)n1 * CH + cg) = o;
    }
}

extern "C" void kernel_launch(void* const* d_in, const int* in_sizes, int n_in,
                              void* d_out, int out_size, void* d_ws, size_t ws_size,
                              hipStream_t stream)
{
    const float* x     = (const float*)d_in[0];
    const void*  edges = d_in[1];
    const float* Wl    = (const float*)d_in[2];
    const float* Wr    = (const float*)d_in[3];
    const float* b     = (const float*)d_in[4];
    float*       out   = (float*)d_out;

    const int n_nodes = in_sizes[0] / CH;
    const int n_edges = in_sizes[1] / 2;
    const long long n_x = (long long)n_nodes * CH;

    char* ws = (char*)d_ws;
    const size_t ints_n = (size_t)n_nodes * sizeof(int);
    const int    nscan  = (n_nodes + SC_T * SC_I - 1) / (SC_T * SC_I);
    const size_t sort_need = 3 * ints_n + 1024 * sizeof(int)
                           + (size_t)n_edges * sizeof(int);
    const size_t xb_off    = (sort_need + 255) & ~(size_t)255;
    const size_t full_need = xb_off + (size_t)n_x * sizeof(ushort);

    if (ws_size >= sort_need && nscan <= 1024) {
        int* deg    = (int*)ws;
        int* offs   = (int*)(ws + ints_n);
        int* cursor = (int*)(ws + 2 * ints_n);
        int* bsums  = (int*)(ws + 3 * ints_n);
        int* sorted = (int*)(ws + 3 * ints_n + 1024 * sizeof(int));
        const bool bf16_path = (ws_size >= full_need);
        ushort* xb = (ushort*)(ws + xb_off);

        hipMemsetAsync(deg, 0, ints_n, stream);

        const int eb = (n_edges + 255) / 256;
        if (bf16_path) {
            const long long cast_blocks = (n_x + 2047) / 2048;
            const int pb = (int)((cast_blocks > eb) ? cast_blocks : eb);
            prep_kernel<<<pb, 256, 0, stream>>>(edges, deg, n_edges, x, xb, n_x);
        } else {
            hist_kernel<<<eb, 256, 0, stream>>>(edges, deg, n_edges);
        }
        scan_blocks<<<nscan, SC_T, 0, stream>>>(deg, offs, bsums, n_nodes);
        fixup_kernel<<<(n_nodes + 255) / 256, 256, 0, stream>>>(offs, bsums, cursor, n_nodes);
        sort_kernel<<<eb, 256, 0, stream>>>(edges, cursor, sorted, n_edges);

        const int ob = (n_nodes + NB - 1) / NB;
        if (bf16_path) {
            fused_bf16_kernel<<<ob, 256, 0, stream>>>(xb, sorted, deg, offs, Wl, Wr, b, out, n_nodes, n_edges);
        } else {
            fused_kernel<<<ob, 256, 0, stream>>>(x, sorted, deg, offs, Wl, Wr, b, out, n_nodes);
        }
    } else {
        float* agg = out;
        float* cnt = (float*)ws;
        hipMemsetAsync(agg, 0, (size_t)n_nodes * CH * sizeof(float), stream);
        hipMemsetAsync(cnt, 0, ints_n, stream);
        scatter_kernel<<<(n_edges + 3) / 4, 256, 0, stream>>>(x, edges, agg, cnt, n_edges);
        sage_out_kernel<<<(n_nodes + FB_NB - 1) / FB_NB, 256, 0, stream>>>(x, agg, cnt, Wl, Wr, b, out, n_nodes);
    }
}

// Round 6
// 307.586 us; speedup vs baseline: 3.0910x; 1.2822x over previous
//
#include <hip/hip_runtime.h>

#define CH 128
#define NB 64
#define LPAD 4
#define LSTR (NB + LPAD)
#define FB_NB 16
#define SC_T 256
#define SC_I 8

typedef __attribute__((ext_vector_type(8))) __bf16 bf16x8;
typedef __attribute__((ext_vector_type(4))) float f32x4;

// ---------------------------------------------------------------------------
// bf16 helpers (RNE)
// ---------------------------------------------------------------------------
__device__ __forceinline__ unsigned bf16rne(float f) {
    unsigned u = __float_as_uint(f);
    return (u + 0x7FFFu + ((u >> 16) & 1u)) >> 16;
}
__device__ __forceinline__ unsigned pack2bf(float lo, float hi) {
    return bf16rne(lo) | (bf16rne(hi) << 16);
}

// int64-vs-int32 edge_index detection (odd words all zero => int64 < 2^31)
__device__ __forceinline__ int detect_f(const void* edges) {
    const int* ei = (const int*)edges;
    int hi_zero = (ei[1] == 0) & (ei[3] == 0) & (ei[5] == 0) & (ei[7] == 0);
    int lo_any  = (ei[0] | ei[2] | ei[4] | ei[6]) != 0;
    return hi_zero & lo_any;
}
__device__ __forceinline__ int load_dst(const void* edges, int e, int n_edges, int f) {
    const int* p = (const int*)edges;
    return f ? p[2 * (e + n_edges)] : p[e + n_edges];
}
__device__ __forceinline__ int load_src(const void* edges, int e, int f) {
    const int* p = (const int*)edges;
    return f ? p[2 * e] : p[e];
}

// ---------------------------------------------------------------------------
// 1) fused prep: degree histogram + x -> bf16 cast
// ---------------------------------------------------------------------------
__global__ __launch_bounds__(256) void prep_kernel(
    const void* __restrict__ edges,
    int* __restrict__ deg, int n_edges,
    const float* __restrict__ x, ushort* __restrict__ xb, long long n_x)
{
    const int f = detect_f(edges);
    long long i = (long long)blockIdx.x * 256 + threadIdx.x;
    if (i < n_edges) atomicAdd(&deg[load_dst(edges, (int)i, n_edges, f)], 1);
    long long base = i * 8;
    if (base + 8 <= n_x) {
        float4 a = *(const float4*)(x + base);
        float4 c = *(const float4*)(x + base + 4);
        uint4 o;
        o.x = pack2bf(a.x, a.y);
        o.y = pack2bf(a.z, a.w);
        o.z = pack2bf(c.x, c.y);
        o.w = pack2bf(c.z, c.w);
        *(uint4*)(xb + base) = o;
    } else {
        for (long long j = base; j < n_x; ++j) xb[j] = (ushort)bf16rne(x[j]);
    }
}

// W transpose+cast: Wt[j][k] (j=out ch, k=0..255; k<128 -> Wl, else Wr), bf16
__global__ __launch_bounds__(256) void wt_kernel(
    const float* __restrict__ Wl, const float* __restrict__ Wr,
    ushort* __restrict__ Wt)
{
    int idx = blockIdx.x * 256 + threadIdx.x;
    if (idx >= CH * 2 * CH) return;
    int j = idx >> 8, k = idx & 255;
    float v = (k < CH) ? Wl[k * CH + j] : Wr[(k - CH) * CH + j];
    Wt[idx] = (ushort)bf16rne(v);
}

// ---------------------------------------------------------------------------
// 2) exclusive scan of deg -> offs
// ---------------------------------------------------------------------------
__global__ __launch_bounds__(SC_T) void scan_blocks(
    const int* __restrict__ deg, int* __restrict__ offs,
    int* __restrict__ bsums, int n)
{
    __shared__ int s_sum[SC_T];
    const int t = threadIdx.x;
    const int base = blockIdx.x * SC_T * SC_I + t * SC_I;
    int v[SC_I];
    int tsum = 0;
#pragma unroll
    for (int i = 0; i < SC_I; ++i) {
        int idx = base + i;
        v[i] = (idx < n) ? deg[idx] : 0;
        tsum += v[i];
    }
    s_sum[t] = tsum;
    __syncthreads();
    for (int off = 1; off < SC_T; off <<= 1) {
        int val = (t >= off) ? s_sum[t - off] : 0;
        __syncthreads();
        s_sum[t] += val;
        __syncthreads();
    }
    int run = s_sum[t] - tsum;
#pragma unroll
    for (int i = 0; i < SC_I; ++i) {
        int idx = base + i;
        if (idx < n) offs[idx] = run;
        run += v[i];
    }
    if (t == SC_T - 1) bsums[blockIdx.x] = s_sum[t];
}

__global__ __launch_bounds__(256) void fixup_kernel(
    int* __restrict__ offs, const int* __restrict__ bsums,
    int* __restrict__ cursor, int n)
{
    int i = blockIdx.x * 256 + threadIdx.x;
    if (i >= n) return;
    int bucket = i / (SC_T * SC_I);
    int add = 0;
    for (int j = 0; j < bucket; ++j) add += bsums[j];
    int o = offs[i] + add;
    offs[i] = o;
    cursor[i] = o;
}

// ---------------------------------------------------------------------------
// 3) scatter src ids into dst-sorted order
// ---------------------------------------------------------------------------
__global__ __launch_bounds__(256) void sort_kernel(
    const void* __restrict__ edges,
    int* __restrict__ cursor, int* __restrict__ sorted, int n_edges)
{
    const int f = detect_f(edges);
    int e = blockIdx.x * 256 + threadIdx.x;
    if (e >= n_edges) return;
    int d = load_dst(edges, e, n_edges, f);
    int s = load_src(edges, e, f);
    int pos = atomicAdd(&cursor[d], 1);
    sorted[pos] = s;
}

// ---------------------------------------------------------------------------
// 4) persistent fused gather-mean + MFMA GEMM.
//    LDS natural [node][ch] (stride 136 ushort = 272 B, 16B-aligned rows).
//    MFMA 16x16x32 bf16, m97-verified pattern: A = node rows (MxK row-major),
//    B = Wt rows (NxK row-major), C: col=lane&15, row=(lane>>4)*4+reg.
// ---------------------------------------------------------------------------
__global__ __launch_bounds__(256, 4) void fused_mfma_kernel(
    const ushort* __restrict__ xb,
    const int* __restrict__ sorted,
    const int* __restrict__ deg,
    const int* __restrict__ offs,
    const ushort* __restrict__ Wt,
    const float* __restrict__ bias,
    float* __restrict__ out,
    int n_nodes, int nE, int ntiles)
{
    __shared__ ushort s_m[64][136];
    __shared__ ushort s_v[64][136];

    const int tid  = threadIdx.x;
    const int wave = tid >> 6;
    const int lane = tid & 63;
    const int rA   = lane & 15;
    const int gA   = lane >> 4;
    const int oc0  = wave * 32;
    const float b0 = bias[oc0 + rA];
    const float b1 = bias[oc0 + 16 + rA];

    for (int tile = blockIdx.x; tile < ntiles; tile += gridDim.x) {
        const int node0 = tile * NB;
        const int first = node0 + wave * 16;

        // ---- gather phase: wave handles 16 consecutive nodes ----
        if (first < n_nodes) {
            const int nval = min(16, n_nodes - first);

#pragma unroll
            for (int nn = 0; nn < 16; ++nn) {
                int node = min(first + nn, n_nodes - 1);
                unsigned u = *(const unsigned*)(xb + (size_t)node * CH + lane * 2);
                *(unsigned*)&s_v[wave * 16 + nn][lane * 2] = u;
            }

            const int base0 = offs[first];
            const int e_end = (first + nval < n_nodes) ? offs[first + nval] : nE;
            const int Ew      = e_end - base0;
            const int nb_full = Ew >> 4;
            const int rem     = Ew & 15;

            int   nstored = 0;
            int   dcur    = deg[first];
            int   cur_end = base0 + dcur;
            float alo = 0.f, ahi = 0.f;

            int sv_cur = 0, sv_nxt = 0;
            if (Ew > 0) sv_cur = sorted[min(base0 + lane, nE - 1)];

            auto flushfn = [&](int ii) {
                while (ii == cur_end && nstored < nval) {
                    float sc  = 1.0f / fmaxf((float)dcur, 1.0f);
                    *(unsigned*)&s_m[wave * 16 + nstored][lane * 2] =
                        pack2bf(alo * sc, ahi * sc);
                    alo = 0.f; ahi = 0.f;
                    ++nstored;
                    if (nstored < nval) { dcur = deg[first + nstored]; cur_end += dcur; }
                }
            };
            auto issue = [&](unsigned (&U)[16], int bb) {
                if ((bb & 3) == 0) {
                    if (bb > 0) sv_cur = sv_nxt;
                    int c = (bb >> 2) + 1;
                    if (c * 64 < Ew) sv_nxt = sorted[min(base0 + c * 64 + lane, nE - 1)];
                }
                int q = (bb & 3) * 16;
#pragma unroll
                for (int t = 0; t < 16; ++t) {
                    int s = __shfl(sv_cur, q + t);
                    U[t] = *(const unsigned*)(xb + (size_t)s * CH + lane * 2);
                }
            };
            auto accum = [&](unsigned (&U)[16], int bb) {
                int i0 = base0 + bb * 16;
#pragma unroll
                for (int t = 0; t < 16; ++t) {
                    flushfn(i0 + t);
                    alo += __uint_as_float(U[t] << 16);
                    ahi += __uint_as_float(U[t] & 0xFFFF0000u);
                }
            };

            unsigned uA[16], uB[16];
            if (nb_full > 0) issue(uA, 0);
            int bI = 0;
            while (bI < nb_full) {
                if (bI + 1 < nb_full) issue(uB, bI + 1);
                accum(uA, bI);
                ++bI;
                if (bI >= nb_full) break;
                if (bI + 1 < nb_full) issue(uA, bI + 1);
                accum(uB, bI);
                ++bI;
            }

            if (rem > 0) {
                if (nb_full > 0 && (nb_full & 3) == 0) sv_cur = sv_nxt;
                int q = (nb_full & 3) * 16;
                for (int t = 0; t < rem; ++t) {
                    int i = base0 + nb_full * 16 + t;
                    int s = __shfl(sv_cur, q + t);
                    unsigned u = *(const unsigned*)(xb + (size_t)s * CH + lane * 2);
                    flushfn(i);
                    alo += __uint_as_float(u << 16);
                    ahi += __uint_as_float(u & 0xFFFF0000u);
                }
            }
            while (nstored < nval) {
                float sc = 1.0f / fmaxf((float)dcur, 1.0f);
                *(unsigned*)&s_m[wave * 16 + nstored][lane * 2] =
                    pack2bf(alo * sc, ahi * sc);
                alo = 0.f; ahi = 0.f;
                ++nstored;
                if (nstored < nval) dcur = deg[first + nstored];
            }
        }
        __syncthreads();

        // ---- MFMA phase: wave computes all 64 nodes x 32 out-ch ----
        f32x4 acc[4][2];
#pragma unroll
        for (int nt = 0; nt < 4; ++nt) {
            acc[nt][0] = (f32x4){0.f, 0.f, 0.f, 0.f};
            acc[nt][1] = (f32x4){0.f, 0.f, 0.f, 0.f};
        }

#pragma unroll
        for (int ks = 0; ks < 8; ++ks) {
            const int kk = (ks & 3) * 32 + gA * 8;           // LDS element offset
            const ushort (*S)[136] = (ks < 4) ? s_m : s_v;
            const ushort* wrow = Wt + ks * 32 + gA * 8;
            bf16x8 bf0 = __builtin_bit_cast(bf16x8,
                *(const uint4*)(wrow + (oc0 + rA) * 256));
            bf16x8 bf1 = __builtin_bit_cast(bf16x8,
                *(const uint4*)(wrow + (oc0 + 16 + rA) * 256));
#pragma unroll
            for (int nt = 0; nt < 4; ++nt) {
                bf16x8 af = __builtin_bit_cast(bf16x8,
                    *(const uint4*)&S[nt * 16 + rA][kk]);
                acc[nt][0] = __builtin_amdgcn_mfma_f32_16x16x32_bf16(af, bf0, acc[nt][0], 0, 0, 0);
                acc[nt][1] = __builtin_amdgcn_mfma_f32_16x16x32_bf16(af, bf1, acc[nt][1], 0, 0, 0);
            }
        }

#pragma unroll
        for (int nt = 0; nt < 4; ++nt) {
            int nbase = node0 + nt * 16 + gA * 4;
#pragma unroll
            for (int r = 0; r < 4; ++r) {
                int node = nbase + r;
                if (node < n_nodes) {
                    out[(size_t)node * CH + oc0 + rA]      = fmaxf(acc[nt][0][r] + b0, 0.f);
                    out[(size_t)node * CH + oc0 + 16 + rA] = fmaxf(acc[nt][1][r] + b1, 0.f);
                }
            }
        }
        __syncthreads();
    }
}

// ---------------------------------------------------------------------------
// Path B: f32 fused kernel for smaller workspaces (round-5 version).
// ---------------------------------------------------------------------------
__global__ __launch_bounds__(256) void fused_kernel(
    const float* __restrict__ x,
    const int* __restrict__ sorted,
    const int* __restrict__ deg,
    const int* __restrict__ offs,
    const float* __restrict__ Wl,
    const float* __restrict__ Wr,
    const float* __restrict__ b,
    float* __restrict__ out,
    int n_nodes)
{
    __shared__ float s_m[CH][LSTR];
    __shared__ float s_v[CH][LSTR];

    const int node0 = blockIdx.x * NB;
    const int tid   = threadIdx.x;
    const int wave  = tid >> 6;
    const int lane  = tid & 63;

    for (int nn = 0; nn < 16; ++nn) {
        int n    = wave * 16 + nn;
        int node = node0 + n;
        float a0 = 0.f, a1 = 0.f, x0 = 0.f, x1 = 0.f;
        if (node < n_nodes) {
            const float* xr = x + (long long)node * CH;
            x0 = xr[lane];
            x1 = xr[lane + 64];
            int base = offs[node];
            int dg   = deg[node];
            for (int j0 = 0; j0 < dg; j0 += 64) {
                int m  = min(64, dg - j0);
                int sv = (j0 + lane < dg) ? sorted[base + j0 + lane] : 0;
                int jj = 0;
                for (; jj + 8 <= m; jj += 8) {
                    float v0[8], v1[8];
#pragma unroll
                    for (int u = 0; u < 8; ++u) {
                        int s = __shfl(sv, jj + u);
                        const float* p = x + (long long)s * CH;
                        v0[u] = p[lane];
                        v1[u] = p[lane + 64];
                    }
#pragma unroll
                    for (int u = 0; u < 8; ++u) { a0 += v0[u]; a1 += v1[u]; }
                }
                for (; jj < m; ++jj) {
                    int s = __shfl(sv, jj);
                    const float* p = x + (long long)s * CH;
                    a0 += p[lane];
                    a1 += p[lane + 64];
                }
            }
            float inv = 1.0f / fmaxf((float)dg, 1.0f);
            a0 *= inv; a1 *= inv;
        }
        s_m[lane][n]      = a0;
        s_m[lane + 64][n] = a1;
        s_v[lane][n]      = x0;
        s_v[lane + 64][n] = x1;
    }
    __syncthreads();

    const int cg = (tid & 31) * 4;
    const int ng = (tid >> 5) * 8;

    float acc[8][4];
#pragma unroll
    for (int u = 0; u < 8; ++u)
#pragma unroll
        for (int j = 0; j < 4; ++j) acc[u][j] = 0.f;

#pragma unroll 4
    for (int k = 0; k < CH; ++k) {
        const float* mr = &s_m[k][ng];
        const float* vr = &s_v[k][ng];
        float4 wl = *(const float4*)(Wl + k * CH + cg);
        float4 wr = *(const float4*)(Wr + k * CH + cg);
#pragma unroll
        for (int u = 0; u < 8; ++u) {
            float m  = mr[u];
            float xv = vr[u];
            acc[u][0] += m * wl.x + xv * wr.x;
            acc[u][1] += m * wl.y + xv * wr.y;
            acc[u][2] += m * wl.z + xv * wr.z;
            acc[u][3] += m * wl.w + xv * wr.w;
        }
    }

    float4 bb = *(const float4*)(b + cg);
#pragma unroll
    for (int u = 0; u < 8; ++u) {
        int node = node0 + ng + u;
        if (node < n_nodes) {
            float4 o;
            o.x = fmaxf(acc[u][0] + bb.x, 0.0f);
            o.y = fmaxf(acc[u][1] + bb.y, 0.0f);
            o.z = fmaxf(acc[u][2] + bb.z, 0.0f);
            o.w = fmaxf(acc[u][3] + bb.w, 0.0f);
            *(float4*)(out + (long long)node * CH + cg) = o;
        }
    }
}

__global__ __launch_bounds__(256) void hist_kernel(
    const void* __restrict__ edges,
    int* __restrict__ deg, int n_edges)
{
    const int f = detect_f(edges);
    int e = blockIdx.x * 256 + threadIdx.x;
    if (e >= n_edges) return;
    atomicAdd(&deg[load_dst(edges, e, n_edges, f)], 1);
}

// ---------------------------------------------------------------------------
// Path C: atomic fallback (tiny workspace).
// ---------------------------------------------------------------------------
__global__ __launch_bounds__(256) void scatter_kernel(
    const float* __restrict__ x, const void* __restrict__ edges,
    float* __restrict__ agg, float* __restrict__ cnt, int n_edges)
{
    const int f = detect_f(edges);
    int e = blockIdx.x * 4 + (threadIdx.x >> 6);
    if (e >= n_edges) return;
    int lane = threadIdx.x & 63;
    long long s = load_src(edges, e, f);
    long long d = load_dst(edges, e, n_edges, f);
    const float* xs = x + s * (long long)CH;
    float*       ad = agg + d * (long long)CH;
    unsafeAtomicAdd(ad + lane,      xs[lane]);
    unsafeAtomicAdd(ad + lane + 64, xs[lane + 64]);
    if (lane == 0) unsafeAtomicAdd(cnt + d, 1.0f);
}

__global__ __launch_bounds__(256) void sage_out_kernel(
    const float* __restrict__ x, const float* agg, const float* __restrict__ cnt,
    const float* __restrict__ Wl, const float* __restrict__ Wr,
    const float* __restrict__ b, float* out, int n_nodes)
{
    __shared__ float s_mean[FB_NB][CH];
    __shared__ float s_x[FB_NB][CH];
    const int node0 = blockIdx.x * FB_NB;
    const int tid   = threadIdx.x;
    for (int i = tid; i < FB_NB * CH; i += 256) {
        int n = i >> 7, c = i & (CH - 1);
        int node = node0 + n;
        float a = 0.0f, xv = 0.0f, inv = 1.0f;
        if (node < n_nodes) {
            inv = 1.0f / fmaxf(cnt[node], 1.0f);
            a  = agg[(long long)node * CH + c];
            xv = x[(long long)node * CH + c];
        }
        s_mean[n][c] = a * inv;
        s_x[n][c]    = xv;
    }
    __syncthreads();
    const int cg = (tid & 31) * 4, nbase = (tid >> 5) * 2;
    float acc0[4] = {0,0,0,0}, acc1[4] = {0,0,0,0};
#pragma unroll 8
    for (int k = 0; k < CH; ++k) {
        float4 wl = *(const float4*)(Wl + k * CH + cg);
        float4 wr = *(const float4*)(Wr + k * CH + cg);
        float m0 = s_mean[nbase][k],   m1 = s_mean[nbase + 1][k];
        float x0 = s_x[nbase][k],      x1 = s_x[nbase + 1][k];
        acc0[0] += m0*wl.x + x0*wr.x;  acc0[1] += m0*wl.y + x0*wr.y;
        acc0[2] += m0*wl.z + x0*wr.z;  acc0[3] += m0*wl.w + x0*wr.w;
        acc1[0] += m1*wl.x + x1*wr.x;  acc1[1] += m1*wl.y + x1*wr.y;
        acc1[2] += m1*wl.z + x1*wr.z;  acc1[3] += m1*wl.w + x1*wr.w;
    }
    float4 bb = *(const float4*)(b + cg);
    int n0 = node0 + nbase, n1 = n0 + 1;
    if (n0 < n_nodes) {
        float4 o = { fmaxf(acc0[0]+bb.x,0.f), fmaxf(acc0[1]+bb.y,0.f),
                     fmaxf(acc0[2]+bb.z,0.f), fmaxf(acc0[3]+bb.w,0.f) };
        *(float4*)(out + (long long)n0 * CH + cg) = o;
    }
    if (n1 < n_nodes) {
        float4 o = { fmaxf(acc1[0]+bb.x,0.f), fmaxf(acc1[1]+bb.y,0.f),
                     fmaxf(acc1[2]+bb.z,0.f), fmaxf(acc1[3]+bb.w,0.f) };
        *(float4*)(out + (long long)n1 * CH + cg) = o;
    }
}

extern "C" void kernel_launch(void* const* d_in, const int* in_sizes, int n_in,
                              void* d_out, int out_size, void* d_ws, size_t ws_size,
                              hipStream_t stream)
{
    const float* x     = (const float*)d_in[0];
    const void*  edges = d_in[1];
    const float* Wl    = (const float*)d_in[2];
    const float* Wr    = (const float*)d_in[3];
    const float* b     = (const float*)d_in[4];
    float*       out   = (float*)d_out;

    const int n_nodes = in_sizes[0] / CH;
    const int n_edges = in_sizes[1] / 2;
    const long long n_x = (long long)n_nodes * CH;

    char* ws = (char*)d_ws;
    const size_t ints_n = (size_t)n_nodes * sizeof(int);
    const int    nscan  = (n_nodes + SC_T * SC_I - 1) / (SC_T * SC_I);
    const size_t sort_need = 3 * ints_n + 1024 * sizeof(int)
                           + (size_t)n_edges * sizeof(int);
    const size_t xb_off    = (sort_need + 255) & ~(size_t)255;
    const size_t wt_off    = (xb_off + (size_t)n_x * sizeof(ushort) + 255) & ~(size_t)255;
    const size_t full_need = wt_off + (size_t)(CH * 2 * CH) * sizeof(ushort);

    if (ws_size >= sort_need && nscan <= 1024) {
        int* deg    = (int*)ws;
        int* offs   = (int*)(ws + ints_n);
        int* cursor = (int*)(ws + 2 * ints_n);
        int* bsums  = (int*)(ws + 3 * ints_n);
        int* sorted = (int*)(ws + 3 * ints_n + 1024 * sizeof(int));
        const bool bf16_path = (ws_size >= full_need);
        ushort* xb = (ushort*)(ws + xb_off);
        ushort* Wt = (ushort*)(ws + wt_off);

        hipMemsetAsync(deg, 0, ints_n, stream);

        const int eb = (n_edges + 255) / 256;
        if (bf16_path) {
            const long long cast_blocks = (n_x + 2047) / 2048;
            const int pb = (int)((cast_blocks > eb) ? cast_blocks : eb);
            prep_kernel<<<pb, 256, 0, stream>>>(edges, deg, n_edges, x, xb, n_x);
            wt_kernel<<<(CH * 2 * CH + 255) / 256, 256, 0, stream>>>(Wl, Wr, Wt);
        } else {
            hist_kernel<<<eb, 256, 0, stream>>>(edges, deg, n_edges);
        }
        scan_blocks<<<nscan, SC_T, 0, stream>>>(deg, offs, bsums, n_nodes);
        fixup_kernel<<<(n_nodes + 255) / 256, 256, 0, stream>>>(offs, bsums, cursor, n_nodes);
        sort_kernel<<<eb, 256, 0, stream>>>(edges, cursor, sorted, n_edges);

        const int ntiles = (n_nodes + NB - 1) / NB;
        if (bf16_path) {
            const int grid = (ntiles < 1024) ? ntiles : 1024;
            fused_mfma_kernel<<<grid, 256, 0, stream>>>(
                xb, sorted, deg, offs, Wt, b, out, n_nodes, n_edges, ntiles);
        } else {
            fused_kernel<<<ntiles, 256, 0, stream>>>(x, sorted, deg, offs, Wl, Wr, b, out, n_nodes);
        }
    } else {
        float* agg = out;
        float* cnt = (float*)ws;
        hipMemsetAsync(agg, 0, (size_t)n_nodes * CH * sizeof(float), stream);
        hipMemsetAsync(cnt, 0, ints_n, stream);
        scatter_kernel<<<(n_edges + 3) / 4, 256, 0, stream>>>(x, edges, agg, cnt, n_edges);
        sage_out_kernel<<<(n_nodes + FB_NB - 1) / FB_NB, 256, 0, stream>>>(x, agg, cnt, Wl, Wr, b, out, n_nodes);
    }
}

// Round 7
// 225.709 us; speedup vs baseline: 4.2122x; 1.3627x over previous
//
#include <hip/hip_runtime.h>

#define CH 128
#define NB 64
#define LPAD 4
#define LSTR (NB + LPAD)
#define FB_NB 16
#define SC_T 256
#define SC_I 8
#define CSH 10
#define CSZ 1024          // nodes per coarse bucket
#define MAXBINS 512
#define A1_T 1024
#define A1_E 8            // edges per thread in bin_kernel

typedef __attribute__((ext_vector_type(8))) __bf16 bf16x8;
typedef __attribute__((ext_vector_type(4))) float f32x4;

// ---------------------------------------------------------------------------
// bf16 helpers (RNE)
// ---------------------------------------------------------------------------
__device__ __forceinline__ unsigned bf16rne(float f) {
    unsigned u = __float_as_uint(f);
    return (u + 0x7FFFu + ((u >> 16) & 1u)) >> 16;
}
__device__ __forceinline__ unsigned pack2bf(float lo, float hi) {
    return bf16rne(lo) | (bf16rne(hi) << 16);
}

// int64-vs-int32 edge_index detection (odd words all zero => int64 < 2^31)
__device__ __forceinline__ int detect_f(const void* edges) {
    const int* ei = (const int*)edges;
    int hi_zero = (ei[1] == 0) & (ei[3] == 0) & (ei[5] == 0) & (ei[7] == 0);
    int lo_any  = (ei[0] | ei[2] | ei[4] | ei[6]) != 0;
    return hi_zero & lo_any;
}
__device__ __forceinline__ int load_dst(const void* edges, int e, int n_edges, int f) {
    const int* p = (const int*)edges;
    return f ? p[2 * (e + n_edges)] : p[e + n_edges];
}
__device__ __forceinline__ int load_src(const void* edges, int e, int f) {
    const int* p = (const int*)edges;
    return f ? p[2 * e] : p[e];
}

// ---------------------------------------------------------------------------
// degree histogram
// ---------------------------------------------------------------------------
__global__ __launch_bounds__(256) void hist_kernel(
    const void* __restrict__ edges,
    int* __restrict__ deg, int n_edges)
{
    const int f = detect_f(edges);
    int e = blockIdx.x * 256 + threadIdx.x;
    if (e >= n_edges) return;
    atomicAdd(&deg[load_dst(edges, e, n_edges, f)], 1);
}

// x -> bf16 cast (8 elts/thread)
__global__ __launch_bounds__(256) void cast_kernel(
    const float* __restrict__ x, ushort* __restrict__ xb, long long n_x)
{
    long long i = (long long)blockIdx.x * 256 + threadIdx.x;
    long long base = i * 8;
    if (base + 8 <= n_x) {
        float4 a = *(const float4*)(x + base);
        float4 c = *(const float4*)(x + base + 4);
        uint4 o;
        o.x = pack2bf(a.x, a.y);
        o.y = pack2bf(a.z, a.w);
        o.z = pack2bf(c.x, c.y);
        o.w = pack2bf(c.z, c.w);
        *(uint4*)(xb + base) = o;
    } else {
        for (long long j = base; j < n_x; ++j) xb[j] = (ushort)bf16rne(x[j]);
    }
}

// W transpose+cast: Wt[j][k] (j=out ch, k=0..255; k<128 -> Wl, else Wr), bf16
__global__ __launch_bounds__(256) void wt_kernel(
    const float* __restrict__ Wl, const float* __restrict__ Wr,
    ushort* __restrict__ Wt)
{
    int idx = blockIdx.x * 256 + threadIdx.x;
    if (idx >= CH * 2 * CH) return;
    int j = idx >> 8, k = idx & 255;
    float v = (k < CH) ? Wl[k * CH + j] : Wr[(k - CH) * CH + j];
    Wt[idx] = (ushort)bf16rne(v);
}

// ---------------------------------------------------------------------------
// exclusive scan of deg -> offs
// ---------------------------------------------------------------------------
__global__ __launch_bounds__(SC_T) void scan_blocks(
    const int* __restrict__ deg, int* __restrict__ offs,
    int* __restrict__ bsums, int n)
{
    __shared__ int s_sum[SC_T];
    const int t = threadIdx.x;
    const int base = blockIdx.x * SC_T * SC_I + t * SC_I;
    int v[SC_I];
    int tsum = 0;
#pragma unroll
    for (int i = 0; i < SC_I; ++i) {
        int idx = base + i;
        v[i] = (idx < n) ? deg[idx] : 0;
        tsum += v[i];
    }
    s_sum[t] = tsum;
    __syncthreads();
    for (int off = 1; off < SC_T; off <<= 1) {
        int val = (t >= off) ? s_sum[t - off] : 0;
        __syncthreads();
        s_sum[t] += val;
        __syncthreads();
    }
    int run = s_sum[t] - tsum;
#pragma unroll
    for (int i = 0; i < SC_I; ++i) {
        int idx = base + i;
        if (idx < n) offs[idx] = run;
        run += v[i];
    }
    if (t == SC_T - 1) bsums[blockIdx.x] = s_sum[t];
}

// fixup for binned path: finalize offs, seed coarse-bucket cursors
__global__ __launch_bounds__(256) void fixup2_kernel(
    int* __restrict__ offs, const int* __restrict__ bsums,
    int* __restrict__ gcursor, int n)
{
    int i = blockIdx.x * 256 + threadIdx.x;
    if (i >= n) return;
    int bucket = i / (SC_T * SC_I);
    int add = 0;
    for (int j = 0; j < bucket; ++j) add += bsums[j];
    int o = offs[i] + add;
    offs[i] = o;
    if ((i & (CSZ - 1)) == 0) gcursor[i >> CSH] = o;
}

// fixup for legacy sort path: finalize offs, init per-node cursor
__global__ __launch_bounds__(256) void fixup_kernel(
    int* __restrict__ offs, const int* __restrict__ bsums,
    int* __restrict__ cursor, int n)
{
    int i = blockIdx.x * 256 + threadIdx.x;
    if (i >= n) return;
    int bucket = i / (SC_T * SC_I);
    int add = 0;
    for (int j = 0; j < bucket; ++j) add += bsums[j];
    int o = offs[i] + add;
    offs[i] = o;
    cursor[i] = o;
}

// ---------------------------------------------------------------------------
// A1: bin edges into coarse buckets (1024 dst nodes each) with LDS histogram
// + per-(block,bucket) run reservation -> coalesced run writes.
// entry = src | (dst & 1023) << 22   (requires n_nodes < 2^22)
// ---------------------------------------------------------------------------
__global__ __launch_bounds__(A1_T) void bin_kernel(
    const void* __restrict__ edges, int* __restrict__ gcursor,
    unsigned* __restrict__ binned, int n_edges, int nbins)
{
    __shared__ int lcnt[MAXBINS];
    __shared__ int lbase[MAXBINS];
    const int f   = detect_f(edges);
    const int tid = threadIdx.x;
    for (int i = tid; i < nbins; i += A1_T) lcnt[i] = 0;
    __syncthreads();

    int bin[A1_E], lrank[A1_E];
    unsigned ent[A1_E];
    const int e0 = blockIdx.x * (A1_T * A1_E);
#pragma unroll
    for (int j = 0; j < A1_E; ++j) {
        int e = e0 + j * A1_T + tid;
        bin[j] = -1;
        if (e < n_edges) {
            int s = load_src(edges, e, f);
            int d = load_dst(edges, e, n_edges, f);
            bin[j]   = d >> CSH;
            ent[j]   = (unsigned)s | ((unsigned)(d & (CSZ - 1)) << 22);
            lrank[j] = atomicAdd(&lcnt[bin[j]], 1);
        }
    }
    __syncthreads();
    for (int i = tid; i < nbins; i += A1_T)
        lbase[i] = atomicAdd(&gcursor[i], lcnt[i]);
    __syncthreads();
#pragma unroll
    for (int j = 0; j < A1_E; ++j)
        if (bin[j] >= 0) binned[lbase[bin[j]] + lrank[j]] = ent[j];
}

// ---------------------------------------------------------------------------
// A2: within each coarse bucket, slot edges into per-node contiguous ranges.
// One block per bucket; all writes land in the block-exclusive window
// [offs[c*1024], offs[(c+1)*1024]) -> no cross-XCD line ping-pong.
// ---------------------------------------------------------------------------
__global__ __launch_bounds__(CSZ) void sortfine_kernel(
    const unsigned* __restrict__ binned, const int* __restrict__ offs,
    int* __restrict__ sorted, int n_nodes, int n_edges)
{
    __shared__ int cnt[CSZ];
    const int c   = blockIdx.x;
    const int tid = threadIdx.x;
    cnt[tid] = 0;
    __syncthreads();
    const int node0 = c << CSH;
    const int start = offs[node0];
    const int nn1   = (c + 1) << CSH;
    const int end   = (nn1 < n_nodes) ? offs[nn1] : n_edges;
    for (int i = start + tid; i < end; i += CSZ) {
        unsigned ent = binned[i];
        int dl = (int)(ent >> 22);
        int r  = atomicAdd(&cnt[dl], 1);
        sorted[offs[node0 + dl] + r] = (int)(ent & 0x3FFFFFu);
    }
}

// ---------------------------------------------------------------------------
// legacy scatter-sort (tier-3 path)
// ---------------------------------------------------------------------------
__global__ __launch_bounds__(256) void sort_kernel(
    const void* __restrict__ edges,
    int* __restrict__ cursor, int* __restrict__ sorted, int n_edges)
{
    const int f = detect_f(edges);
    int e = blockIdx.x * 256 + threadIdx.x;
    if (e >= n_edges) return;
    int d = load_dst(edges, e, n_edges, f);
    int s = load_src(edges, e, f);
    int pos = atomicAdd(&cursor[d], 1);
    sorted[pos] = s;
}

// ---------------------------------------------------------------------------
// persistent fused gather-mean + MFMA GEMM (unchanged from round 6).
// ---------------------------------------------------------------------------
__global__ __launch_bounds__(256, 4) void fused_mfma_kernel(
    const ushort* __restrict__ xb,
    const int* __restrict__ sorted,
    const int* __restrict__ deg,
    const int* __restrict__ offs,
    const ushort* __restrict__ Wt,
    const float* __restrict__ bias,
    float* __restrict__ out,
    int n_nodes, int nE, int ntiles)
{
    __shared__ ushort s_m[64][136];
    __shared__ ushort s_v[64][136];

    const int tid  = threadIdx.x;
    const int wave = tid >> 6;
    const int lane = tid & 63;
    const int rA   = lane & 15;
    const int gA   = lane >> 4;
    const int oc0  = wave * 32;
    const float b0 = bias[oc0 + rA];
    const float b1 = bias[oc0 + 16 + rA];

    for (int tile = blockIdx.x; tile < ntiles; tile += gridDim.x) {
        const int node0 = tile * NB;
        const int first = node0 + wave * 16;

        if (first < n_nodes) {
            const int nval = min(16, n_nodes - first);

#pragma unroll
            for (int nn = 0; nn < 16; ++nn) {
                int node = min(first + nn, n_nodes - 1);
                unsigned u = *(const unsigned*)(xb + (size_t)node * CH + lane * 2);
                *(unsigned*)&s_v[wave * 16 + nn][lane * 2] = u;
            }

            const int base0 = offs[first];
            const int e_end = (first + nval < n_nodes) ? offs[first + nval] : nE;
            const int Ew      = e_end - base0;
            const int nb_full = Ew >> 4;
            const int rem     = Ew & 15;

            int   nstored = 0;
            int   dcur    = deg[first];
            int   cur_end = base0 + dcur;
            float alo = 0.f, ahi = 0.f;

            int sv_cur = 0, sv_nxt = 0;
            if (Ew > 0) sv_cur = sorted[min(base0 + lane, nE - 1)];

            auto flushfn = [&](int ii) {
                while (ii == cur_end && nstored < nval) {
                    float sc  = 1.0f / fmaxf((float)dcur, 1.0f);
                    *(unsigned*)&s_m[wave * 16 + nstored][lane * 2] =
                        pack2bf(alo * sc, ahi * sc);
                    alo = 0.f; ahi = 0.f;
                    ++nstored;
                    if (nstored < nval) { dcur = deg[first + nstored]; cur_end += dcur; }
                }
            };
            auto issue = [&](unsigned (&U)[16], int bb) {
                if ((bb & 3) == 0) {
                    if (bb > 0) sv_cur = sv_nxt;
                    int c = (bb >> 2) + 1;
                    if (c * 64 < Ew) sv_nxt = sorted[min(base0 + c * 64 + lane, nE - 1)];
                }
                int q = (bb & 3) * 16;
#pragma unroll
                for (int t = 0; t < 16; ++t) {
                    int s = __shfl(sv_cur, q + t);
                    U[t] = *(const unsigned*)(xb + (size_t)s * CH + lane * 2);
                }
            };
            auto accum = [&](unsigned (&U)[16], int bb) {
                int i0 = base0 + bb * 16;
#pragma unroll
                for (int t = 0; t < 16; ++t) {
                    flushfn(i0 + t);
                    alo += __uint_as_float(U[t] << 16);
                    ahi += __uint_as_float(U[t] & 0xFFFF0000u);
                }
            };

            unsigned uA[16], uB[16];
            if (nb_full > 0) issue(uA, 0);
            int bI = 0;
            while (bI < nb_full) {
                if (bI + 1 < nb_full) issue(uB, bI + 1);
                accum(uA, bI);
                ++bI;
                if (bI >= nb_full) break;
                if (bI + 1 < nb_full) issue(uA, bI + 1);
                accum(uB, bI);
                ++bI;
            }

            if (rem > 0) {
                if (nb_full > 0 && (nb_full & 3) == 0) sv_cur = sv_nxt;
                int q = (nb_full & 3) * 16;
                for (int t = 0; t < rem; ++t) {
                    int i = base0 + nb_full * 16 + t;
                    int s = __shfl(sv_cur, q + t);
                    unsigned u = *(const unsigned*)(xb + (size_t)s * CH + lane * 2);
                    flushfn(i);
                    alo += __uint_as_float(u << 16);
                    ahi += __uint_as_float(u & 0xFFFF0000u);
                }
            }
            while (nstored < nval) {
                float sc = 1.0f / fmaxf((float)dcur, 1.0f);
                *(unsigned*)&s_m[wave * 16 + nstored][lane * 2] =
                    pack2bf(alo * sc, ahi * sc);
                alo = 0.f; ahi = 0.f;
                ++nstored;
                if (nstored < nval) dcur = deg[first + nstored];
            }
        }
        __syncthreads();

        f32x4 acc[4][2];
#pragma unroll
        for (int nt = 0; nt < 4; ++nt) {
            acc[nt][0] = (f32x4){0.f, 0.f, 0.f, 0.f};
            acc[nt][1] = (f32x4){0.f, 0.f, 0.f, 0.f};
        }

#pragma unroll
        for (int ks = 0; ks < 8; ++ks) {
            const int kk = (ks & 3) * 32 + gA * 8;
            const ushort (*S)[136] = (ks < 4) ? s_m : s_v;
            const ushort* wrow = Wt + ks * 32 + gA * 8;
            bf16x8 bf0 = __builtin_bit_cast(bf16x8,
                *(const uint4*)(wrow + (oc0 + rA) * 256));
            bf16x8 bf1 = __builtin_bit_cast(bf16x8,
                *(const uint4*)(wrow + (oc0 + 16 + rA) * 256));
#pragma unroll
            for (int nt = 0; nt < 4; ++nt) {
                bf16x8 af = __builtin_bit_cast(bf16x8,
                    *(const uint4*)&S[nt * 16 + rA][kk]);
                acc[nt][0] = __builtin_amdgcn_mfma_f32_16x16x32_bf16(af, bf0, acc[nt][0], 0, 0, 0);
                acc[nt][1] = __builtin_amdgcn_mfma_f32_16x16x32_bf16(af, bf1, acc[nt][1], 0, 0, 0);
            }
        }

#pragma unroll
        for (int nt = 0; nt < 4; ++nt) {
            int nbase = node0 + nt * 16 + gA * 4;
#pragma unroll
            for (int r = 0; r < 4; ++r) {
                int node = nbase + r;
                if (node < n_nodes) {
                    out[(size_t)node * CH + oc0 + rA]      = fmaxf(acc[nt][0][r] + b0, 0.f);
                    out[(size_t)node * CH + oc0 + 16 + rA] = fmaxf(acc[nt][1][r] + b1, 0.f);
                }
            }
        }
        __syncthreads();
    }
}

// ---------------------------------------------------------------------------
// Path B: f32 fused kernel for smaller workspaces.
// ---------------------------------------------------------------------------
__global__ __launch_bounds__(256) void fused_kernel(
    const float* __restrict__ x,
    const int* __restrict__ sorted,
    const int* __restrict__ deg,
    const int* __restrict__ offs,
    const float* __restrict__ Wl,
    const float* __restrict__ Wr,
    const float* __restrict__ b,
    float* __restrict__ out,
    int n_nodes)
{
    __shared__ float s_m[CH][LSTR];
    __shared__ float s_v[CH][LSTR];

    const int node0 = blockIdx.x * NB;
    const int tid   = threadIdx.x;
    const int wave  = tid >> 6;
    const int lane  = tid & 63;

    for (int nn = 0; nn < 16; ++nn) {
        int n    = wave * 16 + nn;
        int node = node0 + n;
        float a0 = 0.f, a1 = 0.f, x0 = 0.f, x1 = 0.f;
        if (node < n_nodes) {
            const float* xr = x + (long long)node * CH;
            x0 = xr[lane];
            x1 = xr[lane + 64];
            int base = offs[node];
            int dg   = deg[node];
            for (int j0 = 0; j0 < dg; j0 += 64) {
                int m  = min(64, dg - j0);
                int sv = (j0 + lane < dg) ? sorted[base + j0 + lane] : 0;
                int jj = 0;
                for (; jj + 8 <= m; jj += 8) {
                    float v0[8], v1[8];
#pragma unroll
                    for (int u = 0; u < 8; ++u) {
                        int s = __shfl(sv, jj + u);
                        const float* p = x + (long long)s * CH;
                        v0[u] = p[lane];
                        v1[u] = p[lane + 64];
                    }
#pragma unroll
                    for (int u = 0; u < 8; ++u) { a0 += v0[u]; a1 += v1[u]; }
                }
                for (; jj < m; ++jj) {
                    int s = __shfl(sv, jj);
                    const float* p = x + (long long)s * CH;
                    a0 += p[lane];
                    a1 += p[lane + 64];
                }
            }
            float inv = 1.0f / fmaxf((float)dg, 1.0f);
            a0 *= inv; a1 *= inv;
        }
        s_m[lane][n]      = a0;
        s_m[lane + 64][n] = a1;
        s_v[lane][n]      = x0;
        s_v[lane + 64][n] = x1;
    }
    __syncthreads();

    const int cg = (tid & 31) * 4;
    const int ng = (tid >> 5) * 8;

    float acc[8][4];
#pragma unroll
    for (int u = 0; u < 8; ++u)
#pragma unroll
        for (int j = 0; j < 4; ++j) acc[u][j] = 0.f;

#pragma unroll 4
    for (int k = 0; k < CH; ++k) {
        const float* mr = &s_m[k][ng];
        const float* vr = &s_v[k][ng];
        float4 wl = *(const float4*)(Wl + k * CH + cg);
        float4 wr = *(const float4*)(Wr + k * CH + cg);
#pragma unroll
        for (int u = 0; u < 8; ++u) {
            float m  = mr[u];
            float xv = vr[u];
            acc[u][0] += m * wl.x + xv * wr.x;
            acc[u][1] += m * wl.y + xv * wr.y;
            acc[u][2] += m * wl.z + xv * wr.z;
            acc[u][3] += m * wl.w + xv * wr.w;
        }
    }

    float4 bb = *(const float4*)(b + cg);
#pragma unroll
    for (int u = 0; u < 8; ++u) {
        int node = node0 + ng + u;
        if (node < n_nodes) {
            float4 o;
            o.x = fmaxf(acc[u][0] + bb.x, 0.0f);
            o.y = fmaxf(acc[u][1] + bb.y, 0.0f);
            o.z = fmaxf(acc[u][2] + bb.z, 0.0f);
            o.w = fmaxf(acc[u][3] + bb.w, 0.0f);
            *(float4*)(out + (long long)node * CH + cg) = o;
        }
    }
}

// ---------------------------------------------------------------------------
// Path C: atomic fallback (tiny workspace).
// ---------------------------------------------------------------------------
__global__ __launch_bounds__(256) void scatter_kernel(
    const float* __restrict__ x, const void* __restrict__ edges,
    float* __restrict__ agg, float* __restrict__ cnt, int n_edges)
{
    const int f = detect_f(edges);
    int e = blockIdx.x * 4 + (threadIdx.x >> 6);
    if (e >= n_edges) return;
    int lane = threadIdx.x & 63;
    long long s = load_src(edges, e, f);
    long long d = load_dst(edges, e, n_edges, f);
    const float* xs = x + s * (long long)CH;
    float*       ad = agg + d * (long long)CH;
    unsafeAtomicAdd(ad + lane,      xs[lane]);
    unsafeAtomicAdd(ad + lane + 64, xs[lane + 64]);
    if (lane == 0) unsafeAtomicAdd(cnt + d, 1.0f);
}

__global__ __launch_bounds__(256) void sage_out_kernel(
    const float* __restrict__ x, const float* agg, const float* __restrict__ cnt,
    const float* __restrict__ Wl, const float* __restrict__ Wr,
    const float* __restrict__ b, float* out, int n_nodes)
{
    __shared__ float s_mean[FB_NB][CH];
    __shared__ float s_x[FB_NB][CH];
    const int node0 = blockIdx.x * FB_NB;
    const int tid   = threadIdx.x;
    for (int i = tid; i < FB_NB * CH; i += 256) {
        int n = i >> 7, c = i & (CH - 1);
        int node = node0 + n;
        float a = 0.0f, xv = 0.0f, inv = 1.0f;
        if (node < n_nodes) {
            inv = 1.0f / fmaxf(cnt[node], 1.0f);
            a  = agg[(long long)node * CH + c];
            xv = x[(long long)node * CH + c];
        }
        s_mean[n][c] = a * inv;
        s_x[n][c]    = xv;
    }
    __syncthreads();
    const int cg = (tid & 31) * 4, nbase = (tid >> 5) * 2;
    float acc0[4] = {0,0,0,0}, acc1[4] = {0,0,0,0};
#pragma unroll 8
    for (int k = 0; k < CH; ++k) {
        float4 wl = *(const float4*)(Wl + k * CH + cg);
        float4 wr = *(const float4*)(Wr + k * CH + cg);
        float m0 = s_mean[nbase][k],   m1 = s_mean[nbase + 1][k];
        float x0 = s_x[nbase][k],      x1 = s_x[nbase + 1][k];
        acc0[0] += m0*wl.x + x0*wr.x;  acc0[1] += m0*wl.y + x0*wr.y;
        acc0[2] += m0*wl.z + x0*wr.z;  acc0[3] += m0*wl.w + x0*wr.w;
        acc1[0] += m1*wl.x + x1*wr.x;  acc1[1] += m1*wl.y + x1*wr.y;
        acc1[2] += m1*wl.z + x1*wr.z;  acc1[3] += m1*wl.w + x1*wr.w;
    }
    float4 bb = *(const float4*)(b + cg);
    int n0 = node0 + nbase, n1 = n0 + 1;
    if (n0 < n_nodes) {
        float4 o = { fmaxf(acc0[0]+bb.x,0.f), fmaxf(acc0[1]+bb.y,0.f),
                     fmaxf(acc0[2]+bb.z,0.f), fmaxf(acc0[3]+bb.w,0.f) };
        *(float4*)(out + (long long)n0 * CH + cg) = o;
    }
    if (n1 < n_nodes) {
        float4 o = { fmaxf(acc1[0]+bb.x,0.f), fmaxf(acc1[1]+bb.y,0.f),
                     fmaxf(acc1[2]+bb.z,0.f), fmaxf(acc1[3]+bb.w,0.f) };
        *(float4*)(out + (long long)n1 * CH + cg) = o;
    }
}

extern "C" void kernel_launch(void* const* d_in, const int* in_sizes, int n_in,
                              void* d_out, int out_size, void* d_ws, size_t ws_size,
                              hipStream_t stream)
{
    const float* x     = (const float*)d_in[0];
    const void*  edges = d_in[1];
    const float* Wl    = (const float*)d_in[2];
    const float* Wr    = (const float*)d_in[3];
    const float* b     = (const float*)d_in[4];
    float*       out   = (float*)d_out;

    const int n_nodes = in_sizes[0] / CH;
    const int n_edges = in_sizes[1] / 2;
    const long long n_x = (long long)n_nodes * CH;

    char* ws = (char*)d_ws;
    const size_t ints_n = (size_t)n_nodes * sizeof(int);
    const int    nscan  = (n_nodes + SC_T * SC_I - 1) / (SC_T * SC_I);
    const int    nbins  = (n_nodes + CSZ - 1) >> CSH;

    // tier-1 layout: deg | offs | bsums(4KB) | gcursor(2KB) | sorted | xb∪binned | Wt
    const size_t t1_sorted_off = 2 * ints_n + 1024 * sizeof(int) + MAXBINS * sizeof(int);
    const size_t t1_xb_off     = (t1_sorted_off + (size_t)n_edges * sizeof(int) + 255) & ~(size_t)255;
    const size_t t1_xb_bytes   = ((size_t)n_x * sizeof(ushort) > (size_t)n_edges * 4)
                               ? (size_t)n_x * sizeof(ushort) : (size_t)n_edges * 4;
    const size_t t1_wt_off     = (t1_xb_off + t1_xb_bytes + 255) & ~(size_t)255;
    const size_t t1_need       = t1_wt_off + (size_t)(CH * 2 * CH) * sizeof(ushort);

    // tier-3 layout (f32 path w/ legacy sort): deg | offs | cursor | bsums | sorted
    const size_t t3_need = 3 * ints_n + 1024 * sizeof(int) + (size_t)n_edges * sizeof(int);

    if (ws_size >= t1_need && nscan <= 1024 && nbins <= MAXBINS && n_nodes < (1 << 22)) {
        int*      deg     = (int*)ws;
        int*      offs    = (int*)(ws + ints_n);
        int*      bsums   = (int*)(ws + 2 * ints_n);
        int*      gcursor = (int*)(ws + 2 * ints_n + 1024 * sizeof(int));
        int*      sorted  = (int*)(ws + t1_sorted_off);
        ushort*   xb      = (ushort*)(ws + t1_xb_off);
        unsigned* binned  = (unsigned*)(ws + t1_xb_off);   // aliases xb (dead after A2)
        ushort*   Wt      = (ushort*)(ws + t1_wt_off);

        hipMemsetAsync(deg, 0, ints_n, stream);

        const int eb = (n_edges + 255) / 256;
        hist_kernel<<<eb, 256, 0, stream>>>(edges, deg, n_edges);
        scan_blocks<<<nscan, SC_T, 0, stream>>>(deg, offs, bsums, n_nodes);
        fixup2_kernel<<<(n_nodes + 255) / 256, 256, 0, stream>>>(offs, bsums, gcursor, n_nodes);

        const int a1b = (n_edges + A1_T * A1_E - 1) / (A1_T * A1_E);
        bin_kernel<<<a1b, A1_T, 0, stream>>>(edges, gcursor, binned, n_edges, nbins);
        sortfine_kernel<<<nbins, CSZ, 0, stream>>>(binned, offs, sorted, n_nodes, n_edges);

        // binned dead; cast x into the same region, plus Wt
        const long long cast_blocks = (n_x + 2047) / 2048;
        cast_kernel<<<(int)cast_blocks, 256, 0, stream>>>(x, xb, n_x);
        wt_kernel<<<(CH * 2 * CH + 255) / 256, 256, 0, stream>>>(Wl, Wr, Wt);

        const int ntiles = (n_nodes + NB - 1) / NB;
        const int grid   = (ntiles < 1024) ? ntiles : 1024;
        fused_mfma_kernel<<<grid, 256, 0, stream>>>(
            xb, sorted, deg, offs, Wt, b, out, n_nodes, n_edges, ntiles);
    } else if (ws_size >= t3_need && nscan <= 1024) {
        int* deg    = (int*)ws;
        int* offs   = (int*)(ws + ints_n);
        int* cursor = (int*)(ws + 2 * ints_n);
        int* bsums  = (int*)(ws + 3 * ints_n);
        int* sorted = (int*)(ws + 3 * ints_n + 1024 * sizeof(int));

        hipMemsetAsync(deg, 0, ints_n, stream);
        const int eb = (n_edges + 255) / 256;
        hist_kernel<<<eb, 256, 0, stream>>>(edges, deg, n_edges);
        scan_blocks<<<nscan, SC_T, 0, stream>>>(deg, offs, bsums, n_nodes);
        fixup_kernel<<<(n_nodes + 255) / 256, 256, 0, stream>>>(offs, bsums, cursor, n_nodes);
        sort_kernel<<<eb, 256, 0, stream>>>(edges, cursor, sorted, n_edges);
        fused_kernel<<<(n_nodes + NB - 1) / NB, 256, 0, stream>>>(
            x, sorted, deg, offs, Wl, Wr, b, out, n_nodes);
    } else {
        float* agg = out;
        float* cnt = (float*)ws;
        hipMemsetAsync(agg, 0, (size_t)n_nodes * CH * sizeof(float), stream);
        hipMemsetAsync(cnt, 0, ints_n, stream);
        scatter_kernel<<<(n_edges + 3) / 4, 256, 0, stream>>>(x, edges, agg, cnt, n_edges);
        sage_out_kernel<<<(n_nodes + FB_NB - 1) / FB_NB, 256, 0, stream>>>(x, agg, cnt, Wl, Wr, b, out, n_nodes);
    }
}